// Round 7
// baseline (613.172 us; speedup 1.0000x reference)
//
#include <hip/hip_runtime.h>
#include <hip/hip_bf16.h>
#include <math.h>

// InvGraphConv: SplineCNN block on MI355X.
// N=20000, E=320000, D=3, KS=5 -> K=125, S=8, Fin=Fout=32, hidden=64.
//
// R7: L3-resident z chunks. Channel-split CH=16 (125*16 cols = 125 exact
// 16-col tiles): conv2 = 4 splits x 80MB, conv3 = 2 splits x 80MB. Each
// split's zgemm-write -> msgA-read round trip stays in Infinity Cache.
// zgemm LDS epilogue padded to stride 72 (aligned, <=2-way banks).

typedef short  s16x8 __attribute__((ext_vector_type(8)));
typedef float  f32x4 __attribute__((ext_vector_type(4)));

__device__ __forceinline__ unsigned short f2b(float f) {
    __hip_bfloat16 h = __float2bfloat16(f);
    return __builtin_bit_cast(unsigned short, h);
}
__device__ __forceinline__ unsigned short f2h(float f) {
    _Float16 h = (_Float16)f;
    return __builtin_bit_cast(unsigned short, h);
}
__device__ __forceinline__ float h2f(unsigned short u) {
    _Float16 h = __builtin_bit_cast(_Float16, u);
    return (float)h;
}

__device__ __forceinline__ void spline8(const float u0, const float u1, const float u2,
                                        float* __restrict__ b, int* __restrict__ id) {
    const float u[3] = {u0, u1, u2};
    const int strides[3] = {25, 5, 1};
    float fr[3];
    int   i0[3];
#pragma unroll
    for (int d = 0; d < 3; ++d) {
        float p = u[d] * 4.0f;
        float f = floorf(p);
        f = fminf(fmaxf(f, 0.0f), 3.0f);
        i0[d] = (int)f;
        fr[d] = p - f;
    }
#pragma unroll
    for (int s = 0; s < 8; ++s) {
        float bb = 1.0f;
        int   ii = 0;
#pragma unroll
        for (int d = 0; d < 3; ++d) {
            int c = (s >> d) & 1;
            bb *= c ? fr[d] : (1.0f - fr[d]);
            ii += (i0[d] + c) * strides[d];
        }
        b[s] = bb;
        id[s] = ii;
    }
}

__global__ void hist_kernel(const int* __restrict__ row, const int* __restrict__ col,
                            int* __restrict__ histR, int* __restrict__ histC, int E) {
    int e = blockIdx.x * blockDim.x + threadIdx.x;
    if (e >= E) return;
    atomicAdd(&histR[row[e]], 1);
    atomicAdd(&histC[col[e]], 1);
}

// single-block exclusive scan of hist[N] -> out1 (and optional copy out2)
__global__ __launch_bounds__(1024) void scan_kernel(const int* __restrict__ hist,
                                                    int* __restrict__ out1,
                                                    int* __restrict__ out2, int N) {
    __shared__ int wsum[16];
    __shared__ int carry;
    int t = threadIdx.x, lane = t & 63, w = t >> 6;
    if (t == 0) carry = 0;
    __syncthreads();
    for (int base = 0; base < N; base += 1024) {
        int i = base + t;
        int v = (i < N) ? hist[i] : 0;
        int sc = v;
#pragma unroll
        for (int off = 1; off < 64; off <<= 1) {
            int u = __shfl_up(sc, off);
            if (lane >= off) sc += u;
        }
        if (lane == 63) wsum[w] = sc;
        __syncthreads();
        if (w == 0 && lane < 16) {
            int s = wsum[lane];
#pragma unroll
            for (int off = 1; off < 16; off <<= 1) {
                int u = __shfl_up(s, off);
                if (lane >= off) s += u;
            }
            wsum[lane] = s;
        }
        __syncthreads();
        int woff = (w > 0 ? wsum[w - 1] : 0) + carry;
        int excl = woff + sc - v;
        if (i < N) {
            out1[i] = excl;
            if (out2) out2[i] = excl;
        }
        __syncthreads();
        if (t == 0) carry += wsum[15];
        __syncthreads();
    }
}

// dual scatter: jc = col-sorted slot, jr = row-sorted slot; perm[jr]=jc.
__global__ void scatter_kernel(const int* __restrict__ row, const int* __restrict__ col,
                               int* __restrict__ cursorC, int* __restrict__ cursorR,
                               int* __restrict__ jpos, int* __restrict__ colS,
                               int* __restrict__ perm, int E) {
    int e = blockIdx.x * blockDim.x + threadIdx.x;
    if (e >= E) return;
    int c = col[e], r = row[e];
    int jc = atomicAdd(&cursorC[c], 1);
    int jr = atomicAdd(&cursorR[r], 1);
    jpos[e] = jc;
    colS[jc] = c;
    perm[jr] = jc;
}

__global__ void basis1_kernel(const float* __restrict__ pseudo, const int* __restrict__ jpos,
                              float* __restrict__ basis, unsigned char* __restrict__ idxb, int E) {
    int e = blockIdx.x * blockDim.x + threadIdx.x;
    if (e >= E) return;
    float b[8]; int id[8];
    spline8(pseudo[e * 3 + 0], pseudo[e * 3 + 1], pseudo[e * 3 + 2], b, id);
    int j = jpos ? jpos[e] : e;
#pragma unroll
    for (int s = 0; s < 8; ++s) { basis[(size_t)j * 8 + s] = b[s]; idxb[(size_t)j * 8 + s] = (unsigned char)id[s]; }
}

__global__ void basis2_kernel(const float* __restrict__ pseudo, const float* __restrict__ t,
                              const int* __restrict__ row, const int* __restrict__ col,
                              const int* __restrict__ jpos,
                              float* __restrict__ basis, unsigned char* __restrict__ idxb, int E) {
    int e = blockIdx.x * blockDim.x + threadIdx.x;
    if (e >= E) return;
    int r = row[e], c = col[e];
    float u[3];
#pragma unroll
    for (int d = 0; d < 3; ++d) {
        float v = pseudo[e * 3 + d] + t[c * 3 + d] - t[r * 3 + d];
        u[d] = fminf(fmaxf(v, 0.0f), 1.0f);
    }
    float b[8]; int id[8];
    spline8(u[0], u[1], u[2], b, id);
    int j = jpos ? jpos[e] : e;
#pragma unroll
    for (int s = 0; s < 8; ++s) { basis[(size_t)j * 8 + s] = b[s]; idxb[(size_t)j * 8 + s] = (unsigned char)id[s]; }
}

__global__ void castbf_kernel(const float* __restrict__ in, unsigned short* __restrict__ out,
                              int n) {
    int t = blockIdx.x * blockDim.x + threadIdx.x;
    if (t < n) out[t] = f2b(in[t]);
}

// Pack W [Kc][Fin][Fout] fp32 -> MFMA B-fragments bf16, channel-split order:
// global col c' = (o/CH)*(Kc*CH) + k*CH + o%CH.
__global__ void pack_w_kernel(const float* __restrict__ W, unsigned short* __restrict__ BF,
                              int Kc, int Fin, int Fout, int ksteps, int CH) {
    int t = blockIdx.x * blockDim.x + threadIdx.x;
    int total = Kc * Fout * Fin;
    if (t >= total) return;
    int c = t / Fin;
    int i = t % Fin;
    int kk = c / Fout, o = c % Fout;
    int split = o / CH;
    int cp = split * (Kc * CH) + kk * CH + (o % CH);
    int ct = cp >> 4, lr = cp & 15;
    int step = i >> 5, rem = i & 31, lg = rem >> 3, jj = rem & 7;
    size_t dst = ((((size_t)ct * ksteps + step) * 4 + lg) * 16 + lr) * 8 + jj;
    BF[dst] = f2b(W[((size_t)kk * Fin + i) * Fout + o]);
}

// z = A @ B via mfma_f32_16x16x32_bf16 -> fp16 Z [M][zld].
// 128 rows/block (4 waves x 2 row-frags), 64 cols/block (4 col-frags).
// LDS-bounce epilogue, stride 72 (144B: 16B-aligned rows, <=2-way banks).
template<int KSTEPS>
__global__ __launch_bounds__(256) void zgemm_kernel(
        const unsigned short* __restrict__ A, int M,
        const unsigned short* __restrict__ BF,
        unsigned short* __restrict__ Z, int zld, int ct0, int zct) {
    __shared__ unsigned short ztile[128 * 72];
    int w = threadIdx.x >> 6, l = threadIdx.x & 63;
    int lr = l & 15, lg = l >> 4;
    int base = blockIdx.x * 128;
    const int KD = KSTEPS * 32;
    f32x4 acc0[4], acc1[4];
#pragma unroll
    for (int cf = 0; cf < 4; ++cf) { acc0[cf] = (f32x4){0,0,0,0}; acc1[cf] = (f32x4){0,0,0,0}; }
    int arow0 = base + w * 16 + lr;      if (arow0 > M - 1) arow0 = M - 1;
    int arow1 = base + 64 + w * 16 + lr; if (arow1 > M - 1) arow1 = M - 1;
#pragma unroll
    for (int step = 0; step < KSTEPS; ++step) {
        s16x8 a0 = *(const s16x8*)(A + (size_t)arow0 * KD + step * 32 + lg * 8);
        s16x8 a1 = *(const s16x8*)(A + (size_t)arow1 * KD + step * 32 + lg * 8);
#pragma unroll
        for (int cf = 0; cf < 4; ++cf) {
            int ctl = blockIdx.y * 4 + cf;
            if (ctl < zct) {
                int ctg = ct0 + ctl;
                const unsigned short* bp =
                    BF + ((((size_t)ctg * KSTEPS + step) * 4 + lg) * 16 + lr) * 8;
                s16x8 b = *(const s16x8*)bp;
                acc0[cf] = __builtin_amdgcn_mfma_f32_16x16x32_bf16(a0, b, acc0[cf], 0, 0, 0);
                acc1[cf] = __builtin_amdgcn_mfma_f32_16x16x32_bf16(a1, b, acc1[cf], 0, 0, 0);
            }
        }
    }
    // acc -> LDS fp16 tile
#pragma unroll
    for (int cf = 0; cf < 4; ++cf) {
        int colL = cf * 16 + lr;
#pragma unroll
        for (int r = 0; r < 4; ++r) {
            int rl0 = w * 16 + lg * 4 + r;
            ztile[rl0 * 72 + colL] = f2h(acc0[cf][r]);
            ztile[(rl0 + 64) * 72 + colL] = f2h(acc1[cf][r]);
        }
    }
    __syncthreads();
    // coalesced copy out: 128 rows x 8 uint4
    int rows_in = M - base; if (rows_in > 128) rows_in = 128;
    int valid_cols = (zct - blockIdx.y * 4) * 16; if (valid_cols > 64) valid_cols = 64;
    int bcol = blockIdx.y * 64;
    for (int i = threadIdx.x; i < 128 * 8; i += 256) {
        int rl = i >> 3, cq = (i & 7) * 8;
        if (rl < rows_in && cq < valid_cols) {
            uint4 v = *(const uint4*)(ztile + rl * 72 + cq);
            *(uint4*)(Z + (size_t)(base + rl) * zld + bcol + cq) = v;
        }
    }
}

// phase A: block stages NODES col-nodes' z rows (125*CH fp16 each) into LDS,
// then each CH-lane group processes edges (col-sorted) -> msg fp16, plain store.
template<int CH, int NODES>
__global__ __launch_bounds__(256) void msgA_kernel(
        const unsigned short* __restrict__ z,
        const float* __restrict__ basis, const unsigned char* __restrict__ idxb,
        const int* __restrict__ cstart, const int* __restrict__ colS,
        unsigned short* __restrict__ msg, int msgld, int coff, int N, int E) {
    const int ROW = 125 * CH;
    __shared__ unsigned short lds[NODES * 125 * CH];
    int n0 = blockIdx.x * NODES;
    if (n0 >= N) return;
    int rows = N - n0; if (rows > NODES) rows = NODES;
    int nv4 = rows * ROW / 8;
    const uint4* src = (const uint4*)(z + (size_t)n0 * ROW);
    uint4* dst = (uint4*)lds;
    for (int i = threadIdx.x; i < nv4; i += 256) dst[i] = src[i];
    __syncthreads();
    int estart = cstart[n0];
    int eend = (n0 + NODES < N) ? cstart[n0 + NODES] : E;
    const int NG = 256 / CH;
    int g = threadIdx.x / CH, l = threadIdx.x % CH;
    for (int j = estart + g; j < eend; j += NG) {
        int node = colS[j] - n0;
        const float4* bp = (const float4*)(basis + (size_t)j * 8);
        float4 b0 = bp[0], b1v = bp[1];
        const uchar4* ip = (const uchar4*)(idxb + (size_t)j * 8);
        uchar4 i0 = ip[0], i1 = ip[1];
        const unsigned short* zr = lds + node * ROW;
        float m = b0.x * h2f(zr[i0.x * CH + l]) + b0.y * h2f(zr[i0.y * CH + l])
                + b0.z * h2f(zr[i0.z * CH + l]) + b0.w * h2f(zr[i0.w * CH + l])
                + b1v.x * h2f(zr[i1.x * CH + l]) + b1v.y * h2f(zr[i1.y * CH + l])
                + b1v.z * h2f(zr[i1.z * CH + l]) + b1v.w * h2f(zr[i1.w * CH + l]);
        msg[(size_t)j * msgld + coff + l] = f2h(m);
    }
}

// phase B conv1 (fused): W1 (125x64 fp32, 32KB) in LDS; wave per row-node.
__global__ __launch_bounds__(256) void phaseB1_kernel(
        const float* __restrict__ W1, const float* __restrict__ basis,
        const unsigned char* __restrict__ idxb, const int* __restrict__ perm,
        const int* __restrict__ rowStart, const int* __restrict__ histR,
        const float* __restrict__ b1, unsigned short* __restrict__ h1b, int N) {
    __shared__ float w[125 * 64];
    for (int i = threadIdx.x; i < 125 * 64; i += 256) w[i] = W1[i];
    __syncthreads();
    int n = blockIdx.x * 4 + (threadIdx.x >> 6);
    if (n >= N) return;
    int l = threadIdx.x & 63;
    int s0 = rowStart[n], cnt = histR[n];
    float a = 0.0f;
    for (int base = 0; base < cnt; base += 64) {
        int c = cnt - base < 64 ? cnt - base : 64;
        int pv = (l < c) ? perm[s0 + base + l] : 0;
        for (int i = 0; i < c; ++i) {
            int slot = __shfl(pv, i);
            const float4* bp = (const float4*)(basis + (size_t)slot * 8);
            float4 b0 = bp[0], b1v = bp[1];
            const uchar4* ip = (const uchar4*)(idxb + (size_t)slot * 8);
            uchar4 i0 = ip[0], i1 = ip[1];
            a += b0.x * w[i0.x * 64 + l] + b0.y * w[i0.y * 64 + l]
               + b0.z * w[i0.z * 64 + l] + b0.w * w[i0.w * 64 + l]
               + b1v.x * w[i1.x * 64 + l] + b1v.y * w[i1.y * 64 + l]
               + b1v.z * w[i1.z * 64 + l] + b1v.w * w[i1.w * 64 + l];
        }
    }
    float v = a / fmaxf((float)cnt, 1.0f) + b1[l];
    v = (v > 0.0f) ? v : (expf(v) - 1.0f);
    h1b[(size_t)n * 64 + l] = f2b(v);
}

// phase B, 64ch: wave per row-node; fused mean+bias+elu -> h2 fp32.
__global__ __launch_bounds__(256) void phaseB64_kernel(
        const unsigned short* __restrict__ msg, const int* __restrict__ perm,
        const int* __restrict__ rowStart, const int* __restrict__ histR,
        const float* __restrict__ bias, float* __restrict__ outF, int N) {
    int n = blockIdx.x * 4 + (threadIdx.x >> 6);
    if (n >= N) return;
    int l = threadIdx.x & 63;
    int s0 = rowStart[n], cnt = histR[n];
    float a = 0.0f;
    for (int base = 0; base < cnt; base += 64) {
        int c = cnt - base < 64 ? cnt - base : 64;
        int pv = (l < c) ? perm[s0 + base + l] : 0;
        for (int i = 0; i < c; ++i) {
            int slot = __shfl(pv, i);
            a += h2f(msg[(size_t)slot * 64 + l]);
        }
    }
    float v = a / fmaxf((float)cnt, 1.0f) + bias[l];
    v = (v > 0.0f) ? v : (expf(v) - 1.0f);
    outF[(size_t)n * 64 + l] = v;
}

// phase B, 32ch: half-wave per row-node; fused mean+bias -> out fp32.
__global__ __launch_bounds__(256) void phaseB32_kernel(
        const unsigned short* __restrict__ msg, const int* __restrict__ perm,
        const int* __restrict__ rowStart, const int* __restrict__ histR,
        const float* __restrict__ bias, float* __restrict__ out, int N) {
    int n = blockIdx.x * 8 + (threadIdx.x >> 5);
    if (n >= N) return;
    int l = threadIdx.x & 31;
    int s0 = rowStart[n], cnt = histR[n];
    float a = 0.0f;
    for (int base = 0; base < cnt; base += 32) {
        int c = cnt - base < 32 ? cnt - base : 32;
        int pv = (l < c) ? perm[s0 + base + l] : 0;
        for (int i = 0; i < c; ++i) {
            int slot = __shfl(pv, i, 32);
            a += h2f(msg[(size_t)slot * 32 + l]);
        }
    }
    out[(size_t)n * 32 + l] = a / fmaxf((float)cnt, 1.0f) + bias[l];
}

// stn3 + stn4 per node
__global__ __launch_bounds__(64) void stn34_kernel(
        const float* __restrict__ h2, const float* __restrict__ w3,
        const float* __restrict__ b3, const float* __restrict__ w4,
        const float* __restrict__ b4, float* __restrict__ t, int N) {
    int n = blockIdx.x;
    int o = threadIdx.x;
    __shared__ float sh[64];
    __shared__ float sh3[64];
    sh[o] = h2[n * 64 + o];
    __syncthreads();
    float v = b3[o];
#pragma unroll
    for (int i = 0; i < 64; ++i) v += sh[i] * w3[i * 64 + o];
    v = (v > 0.0f) ? v : (expf(v) - 1.0f);
    sh3[o] = v;
    __syncthreads();
    if (o < 3) {
        float tv = b4[o];
#pragma unroll
        for (int i = 0; i < 64; ++i) tv += sh3[i] * w4[i * 3 + o];
        t[n * 3 + o] = tv;
    }
}

// ---- minimal fallback (only if ws is tiny; direct, correct) ----
__global__ __launch_bounds__(256) void conv1_at_kernel(
        const float* __restrict__ basis, const unsigned char* __restrict__ idxb,
        const int* __restrict__ row, const float* __restrict__ W1,
        float* __restrict__ acc, int E) {
    int j = blockIdx.x * 4 + (threadIdx.x >> 6);
    if (j >= E) return;
    int l = threadIdx.x & 63;
    float m = 0.0f;
#pragma unroll
    for (int s = 0; s < 8; ++s) m += basis[(size_t)j * 8 + s] * W1[idxb[(size_t)j * 8 + s] * 64 + l];
    atomicAdd(&acc[(size_t)row[j] * 64 + l], m);
}

__global__ __launch_bounds__(256) void conv2f_kernel(
        const float* __restrict__ h1, const float* __restrict__ basis,
        const unsigned char* __restrict__ idxb, const int* __restrict__ row,
        const int* __restrict__ col, const float* __restrict__ W2,
        float* __restrict__ acc, int E) {
    int wid = threadIdx.x >> 6;
    int lane = threadIdx.x & 63;
    int e = blockIdx.x * 4 + wid;
    __shared__ float sh[4][64];
    bool active = (e < E);
    int c = active ? col[e] : 0;
    if (active) sh[wid][lane] = h1[(size_t)c * 64 + lane];
    __syncthreads();
    if (!active) return;
    float m = 0.0f;
#pragma unroll
    for (int s = 0; s < 8; ++s) {
        const float* Wk = W2 + (size_t)idxb[(size_t)e * 8 + s] * 4096;
        float ms = 0.0f;
#pragma unroll
        for (int i = 0; i < 64; ++i) ms += sh[wid][i] * Wk[i * 64 + lane];
        m += basis[(size_t)e * 8 + s] * ms;
    }
    atomicAdd(&acc[(size_t)row[e] * 64 + lane], m);
}

__global__ __launch_bounds__(256) void conv3f_kernel(
        const float* __restrict__ x, const float* __restrict__ basis,
        const unsigned char* __restrict__ idxb, const int* __restrict__ row,
        const int* __restrict__ col, const float* __restrict__ Wc,
        float* __restrict__ acc, int E) {
    int wid = threadIdx.x >> 6;
    int lane = threadIdx.x & 63;
    int e = blockIdx.x * 4 + wid;
    __shared__ float sx[4][32];
    bool active = (e < E);
    int c = active ? col[e] : 0;
    if (active && lane < 32) sx[wid][lane] = x[(size_t)c * 32 + lane];
    __syncthreads();
    int half = lane >> 5;
    int o = lane & 31;
    float m = 0.0f;
    if (active) {
#pragma unroll
        for (int s2 = 0; s2 < 4; ++s2) {
            int s = half * 4 + s2;
            const float* Wk = Wc + (size_t)idxb[(size_t)e * 8 + s] * 1024;
            float ms = 0.0f;
#pragma unroll
            for (int i = 0; i < 32; ++i) ms += sx[wid][i] * Wk[i * 32 + o];
            m += basis[(size_t)e * 8 + s] * ms;
        }
    }
    m += __shfl_xor(m, 32);
    if (active && lane < 32) atomicAdd(&acc[(size_t)row[e] * 32 + o], m);
}

__global__ void finalize_kernel(const float* __restrict__ acc, const int* __restrict__ histR,
                                const float* __restrict__ bias, float* __restrict__ outF,
                                unsigned short* __restrict__ outB,
                                int N, int F, int do_elu) {
    int t = blockIdx.x * blockDim.x + threadIdx.x;
    if (t >= N * F) return;
    int n = t / F, o = t % F;
    float v = acc[t] / fmaxf((float)histR[n], 1.0f) + bias[o];
    if (do_elu) v = (v > 0.0f) ? v : (expf(v) - 1.0f);
    if (outF) outF[t] = v;
    if (outB) outB[t] = f2b(v);
}

extern "C" void kernel_launch(void* const* d_in, const int* in_sizes, int n_in,
                              void* d_out, int out_size, void* d_ws, size_t ws_size,
                              hipStream_t stream) {
    const float* x      = (const float*)d_in[0];
    const int*   ei     = (const int*)d_in[1];
    const float* pseudo = (const float*)d_in[2];
    const float* w1     = (const float*)d_in[3];
    const float* b1     = (const float*)d_in[4];
    const float* w2     = (const float*)d_in[5];
    const float* b2     = (const float*)d_in[6];
    const float* w3     = (const float*)d_in[7];
    const float* b3     = (const float*)d_in[8];
    const float* w4     = (const float*)d_in[9];
    const float* b4     = (const float*)d_in[10];
    const float* wc     = (const float*)d_in[11];
    const float* cb     = (const float*)d_in[12];
    float* out = (float*)d_out;

    const int N = in_sizes[0] / 32;
    const int E = in_sizes[1] / 2;
    const int* row = ei;
    const int* col = ei + E;
    const int KC = 125;
    const int CH = 16;              // channels per split (125*16 cols = 125 tiles)

    char* p = (char*)d_ws;
    // zeroed: histograms
    int* histR = (int*)p; p += (size_t)N * sizeof(int);
    int* histC = (int*)p; p += (size_t)N * sizeof(int);
    size_t zero_bytes = (size_t)(p - (char*)d_ws);
    // non-zeroed
    int* cstart   = (int*)p; p += (size_t)N * sizeof(int);
    int* cursorC  = (int*)p; p += (size_t)N * sizeof(int);
    int* rowStart = (int*)p; p += (size_t)N * sizeof(int);
    int* cursorR  = (int*)p; p += (size_t)N * sizeof(int);
    int* jpos = (int*)p; p += (size_t)E * sizeof(int);
    int* colS = (int*)p; p += (size_t)E * sizeof(int);
    int* perm = (int*)p; p += (size_t)E * sizeof(int);
    float* h2 = (float*)p; p += (size_t)N * 64 * sizeof(float);
    float* tt = (float*)p; p += (size_t)N * 3 * sizeof(float);
    float* basis = (float*)p; p += (size_t)E * 8 * sizeof(float);
    unsigned char* idxb = (unsigned char*)p; p += (size_t)E * 8;
    unsigned short* h1b = (unsigned short*)p; p += (size_t)N * 64 * sizeof(short);
    unsigned short* xb  = (unsigned short*)p; p += (size_t)N * 32 * sizeof(short);
    unsigned short* BF2 = (unsigned short*)p; p += (size_t)KC * 64 * 64 * sizeof(short);
    unsigned short* BF3 = (unsigned short*)p; p += (size_t)KC * 32 * 32 * sizeof(short);
    unsigned short* msg = (unsigned short*)p; p += (size_t)E * 64 * sizeof(short);
    size_t fixed = (size_t)(p - (char*)d_ws);
    size_t zcap = (ws_size > fixed) ? (ws_size - fixed) : 0;
    unsigned short* zbuf = (unsigned short*)p;

    const size_t z_chunk = (size_t)N * KC * CH * sizeof(short);  // 80MB (L3-resident)
    bool fast = zcap >= z_chunk;

    hipMemsetAsync(d_ws, 0, zero_bytes, stream);
    hist_kernel<<<(E + 255) / 256, 256, 0, stream>>>(row, col, histR, histC, E);

    const int MT128 = (N + 127) / 128;

    if (fast) {
        const int H2 = 64 / CH;     // 4 splits for conv2
        const int H3 = 32 / CH;     // 2 splits for conv3
        const int zld = KC * CH;    // 2000
        const int zct = KC * CH / 16;  // 125 col-tiles per split

        pack_w_kernel<<<(KC * 64 * 64 + 255) / 256, 256, 0, stream>>>(w2, BF2, KC, 64, 64, 2, CH);
        pack_w_kernel<<<(KC * 32 * 32 + 255) / 256, 256, 0, stream>>>(wc, BF3, KC, 32, 32, 1, CH);
        castbf_kernel<<<(N * 32 + 255) / 256, 256, 0, stream>>>(x, xb, N * 32);

        scan_kernel<<<1, 1024, 0, stream>>>(histC, cstart, cursorC, N);
        scan_kernel<<<1, 1024, 0, stream>>>(histR, rowStart, cursorR, N);
        scatter_kernel<<<(E + 255) / 256, 256, 0, stream>>>(row, col, cursorC, cursorR,
                                                            jpos, colS, perm, E);
        basis1_kernel<<<(E + 255) / 256, 256, 0, stream>>>(pseudo, jpos, basis, idxb, E);

        // conv1: fully fused phase B
        phaseB1_kernel<<<(N + 3) / 4, 256, 0, stream>>>(w1, basis, idxb, perm, rowStart,
                                                        histR, b1, h1b, N);
        // conv2: 4 x 80MB L3-resident z chunks
        for (int s = 0; s < H2; ++s) {
            dim3 g(MT128, (zct + 3) / 4);
            zgemm_kernel<2><<<g, 256, 0, stream>>>(h1b, N, BF2, zbuf, zld, s * zct, zct);
            msgA_kernel<16, 8><<<(N + 7) / 8, 256, 0, stream>>>(
                zbuf, basis, idxb, cstart, colS, msg, 64, s * CH, N, E);
        }
        phaseB64_kernel<<<(N + 3) / 4, 256, 0, stream>>>(msg, perm, rowStart, histR, b2, h2, N);

        stn34_kernel<<<N, 64, 0, stream>>>(h2, w3, b3, w4, b4, tt, N);
        basis2_kernel<<<(E + 255) / 256, 256, 0, stream>>>(pseudo, tt, row, col, jpos,
                                                           basis, idxb, E);
        // conv3: 2 x 80MB chunks
        for (int s = 0; s < H3; ++s) {
            dim3 g(MT128, (zct + 3) / 4);
            zgemm_kernel<1><<<g, 256, 0, stream>>>(xb, N, BF3, zbuf, zld, s * zct, zct);
            msgA_kernel<16, 8><<<(N + 7) / 8, 256, 0, stream>>>(
                zbuf, basis, idxb, cstart, colS, msg, 32, s * CH, N, E);
        }
        phaseB32_kernel<<<(N + 7) / 8, 256, 0, stream>>>(msg, perm, rowStart, histR, cb, out, N);
    } else {
        // tiny-ws fallback: direct convs with atomics (correct, slow)
        float* acc1 = (float*)msg;                 // alias into msg region
        float* acc2 = acc1 + (size_t)N * 64;
        float* acc3 = acc2 + (size_t)N * 64;
        float* h1f  = acc3 + (size_t)N * 32;
        size_t acc_bytes = (size_t)N * (64 + 64 + 32) * sizeof(float);
        hipMemsetAsync((void*)acc1, 0, acc_bytes, stream);

        basis1_kernel<<<(E + 255) / 256, 256, 0, stream>>>(pseudo, nullptr, basis, idxb, E);
        conv1_at_kernel<<<(E + 3) / 4, 256, 0, stream>>>(basis, idxb, row, w1, acc1, E);
        finalize_kernel<<<(N * 64 + 255) / 256, 256, 0, stream>>>(acc1, histR, b1, h1f, nullptr, N, 64, 1);
        conv2f_kernel<<<(E + 3) / 4, 256, 0, stream>>>(h1f, basis, idxb, row, col, w2, acc2, E);
        finalize_kernel<<<(N * 64 + 255) / 256, 256, 0, stream>>>(acc2, histR, b2, h2, nullptr, N, 64, 1);
        stn34_kernel<<<N, 64, 0, stream>>>(h2, w3, b3, w4, b4, tt, N);
        basis2_kernel<<<(E + 255) / 256, 256, 0, stream>>>(pseudo, tt, row, col, nullptr, basis, idxb, E);
        conv3f_kernel<<<(E + 3) / 4, 256, 0, stream>>>(x, basis, idxb, row, col, wc, acc3, E);
        finalize_kernel<<<(N * 32 + 255) / 256, 256, 0, stream>>>(acc3, histR, cb, out, nullptr, N, 32, 0);
    }
}

// Round 8
// 571.474 us; speedup vs baseline: 1.0730x; 1.0730x over previous
//
#include <hip/hip_runtime.h>
#include <hip/hip_bf16.h>
#include <math.h>

// InvGraphConv: SplineCNN block on MI355X.
// N=20000, E=320000, D=3, KS=5 -> K=125, S=8, Fin=Fout=32, hidden=64.
//
// R8: row-sorted msg layout. msgA (col-order streaming compute) scatters each
// edge's message to its ROW-sorted slot rs[j]; phase B reduces each node's
// messages as a contiguous coalesced stream (no perm indirection, no shfl
// latency chain). conv1 = edge-parallel msgA1 + streaming reduce. stn34 fused
// into conv2's phase B. zgemm: CH=32, 3 launches (R6 config).

typedef short  s16x8 __attribute__((ext_vector_type(8)));
typedef float  f32x4 __attribute__((ext_vector_type(4)));

__device__ __forceinline__ unsigned short f2b(float f) {
    __hip_bfloat16 h = __float2bfloat16(f);
    return __builtin_bit_cast(unsigned short, h);
}
__device__ __forceinline__ unsigned short f2h(float f) {
    _Float16 h = (_Float16)f;
    return __builtin_bit_cast(unsigned short, h);
}
__device__ __forceinline__ float h2f(unsigned short u) {
    _Float16 h = __builtin_bit_cast(_Float16, u);
    return (float)h;
}

__device__ __forceinline__ void spline8(const float u0, const float u1, const float u2,
                                        float* __restrict__ b, int* __restrict__ id) {
    const float u[3] = {u0, u1, u2};
    const int strides[3] = {25, 5, 1};
    float fr[3];
    int   i0[3];
#pragma unroll
    for (int d = 0; d < 3; ++d) {
        float p = u[d] * 4.0f;
        float f = floorf(p);
        f = fminf(fmaxf(f, 0.0f), 3.0f);
        i0[d] = (int)f;
        fr[d] = p - f;
    }
#pragma unroll
    for (int s = 0; s < 8; ++s) {
        float bb = 1.0f;
        int   ii = 0;
#pragma unroll
        for (int d = 0; d < 3; ++d) {
            int c = (s >> d) & 1;
            bb *= c ? fr[d] : (1.0f - fr[d]);
            ii += (i0[d] + c) * strides[d];
        }
        b[s] = bb;
        id[s] = ii;
    }
}

__global__ void hist_kernel(const int* __restrict__ row, const int* __restrict__ col,
                            int* __restrict__ histR, int* __restrict__ histC, int E) {
    int e = blockIdx.x * blockDim.x + threadIdx.x;
    if (e >= E) return;
    atomicAdd(&histR[row[e]], 1);
    atomicAdd(&histC[col[e]], 1);
}

// single-block exclusive scan of hist[N] -> out1 (and optional copy out2)
__global__ __launch_bounds__(1024) void scan_kernel(const int* __restrict__ hist,
                                                    int* __restrict__ out1,
                                                    int* __restrict__ out2, int N) {
    __shared__ int wsum[16];
    __shared__ int carry;
    int t = threadIdx.x, lane = t & 63, w = t >> 6;
    if (t == 0) carry = 0;
    __syncthreads();
    for (int base = 0; base < N; base += 1024) {
        int i = base + t;
        int v = (i < N) ? hist[i] : 0;
        int sc = v;
#pragma unroll
        for (int off = 1; off < 64; off <<= 1) {
            int u = __shfl_up(sc, off);
            if (lane >= off) sc += u;
        }
        if (lane == 63) wsum[w] = sc;
        __syncthreads();
        if (w == 0 && lane < 16) {
            int s = wsum[lane];
#pragma unroll
            for (int off = 1; off < 16; off <<= 1) {
                int u = __shfl_up(s, off);
                if (lane >= off) s += u;
            }
            wsum[lane] = s;
        }
        __syncthreads();
        int woff = (w > 0 ? wsum[w - 1] : 0) + carry;
        int excl = woff + sc - v;
        if (i < N) {
            out1[i] = excl;
            if (out2) out2[i] = excl;
        }
        __syncthreads();
        if (t == 0) carry += wsum[15];
        __syncthreads();
    }
}

// dual scatter: jc = col-sorted slot, jr = row-sorted slot.
// jpos[e]=jc (basis write target); colS[jc]=c; rs[jc]=jr (msg write target).
__global__ void scatter_kernel(const int* __restrict__ row, const int* __restrict__ col,
                               int* __restrict__ cursorC, int* __restrict__ cursorR,
                               int* __restrict__ jpos, int* __restrict__ colS,
                               int* __restrict__ rs, int E) {
    int e = blockIdx.x * blockDim.x + threadIdx.x;
    if (e >= E) return;
    int c = col[e], r = row[e];
    int jc = atomicAdd(&cursorC[c], 1);
    int jr = atomicAdd(&cursorR[r], 1);
    jpos[e] = jc;
    colS[jc] = c;
    rs[jc] = jr;
}

__global__ void basis1_kernel(const float* __restrict__ pseudo, const int* __restrict__ jpos,
                              float* __restrict__ basis, unsigned char* __restrict__ idxb, int E) {
    int e = blockIdx.x * blockDim.x + threadIdx.x;
    if (e >= E) return;
    float b[8]; int id[8];
    spline8(pseudo[e * 3 + 0], pseudo[e * 3 + 1], pseudo[e * 3 + 2], b, id);
    int j = jpos ? jpos[e] : e;
#pragma unroll
    for (int s = 0; s < 8; ++s) { basis[(size_t)j * 8 + s] = b[s]; idxb[(size_t)j * 8 + s] = (unsigned char)id[s]; }
}

__global__ void basis2_kernel(const float* __restrict__ pseudo, const float* __restrict__ t,
                              const int* __restrict__ row, const int* __restrict__ col,
                              const int* __restrict__ jpos,
                              float* __restrict__ basis, unsigned char* __restrict__ idxb, int E) {
    int e = blockIdx.x * blockDim.x + threadIdx.x;
    if (e >= E) return;
    int r = row[e], c = col[e];
    float u[3];
#pragma unroll
    for (int d = 0; d < 3; ++d) {
        float v = pseudo[e * 3 + d] + t[c * 3 + d] - t[r * 3 + d];
        u[d] = fminf(fmaxf(v, 0.0f), 1.0f);
    }
    float b[8]; int id[8];
    spline8(u[0], u[1], u[2], b, id);
    int j = jpos ? jpos[e] : e;
#pragma unroll
    for (int s = 0; s < 8; ++s) { basis[(size_t)j * 8 + s] = b[s]; idxb[(size_t)j * 8 + s] = (unsigned char)id[s]; }
}

__global__ void castbf_kernel(const float* __restrict__ in, unsigned short* __restrict__ out,
                              int n) {
    int t = blockIdx.x * blockDim.x + threadIdx.x;
    if (t < n) out[t] = f2b(in[t]);
}

// Pack W [Kc][Fin][Fout] fp32 -> MFMA B-fragments bf16, channel-split order:
// global col c' = (o/CH)*(Kc*CH) + k*CH + o%CH.
__global__ void pack_w_kernel(const float* __restrict__ W, unsigned short* __restrict__ BF,
                              int Kc, int Fin, int Fout, int ksteps, int CH) {
    int t = blockIdx.x * blockDim.x + threadIdx.x;
    int total = Kc * Fout * Fin;
    if (t >= total) return;
    int c = t / Fin;
    int i = t % Fin;
    int kk = c / Fout, o = c % Fout;
    int split = o / CH;
    int cp = split * (Kc * CH) + kk * CH + (o % CH);
    int ct = cp >> 4, lr = cp & 15;
    int step = i >> 5, rem = i & 31, lg = rem >> 3, jj = rem & 7;
    size_t dst = ((((size_t)ct * ksteps + step) * 4 + lg) * 16 + lr) * 8 + jj;
    BF[dst] = f2b(W[((size_t)kk * Fin + i) * Fout + o]);
}

// z = A @ B via mfma_f32_16x16x32_bf16 -> fp16 Z [M][zld].
// 128 rows/block, LDS-bounce epilogue (stride 72).
template<int KSTEPS>
__global__ __launch_bounds__(256) void zgemm_kernel(
        const unsigned short* __restrict__ A, int M,
        const unsigned short* __restrict__ BF,
        unsigned short* __restrict__ Z, int zld, int ct0, int zct) {
    __shared__ unsigned short ztile[128 * 72];
    int w = threadIdx.x >> 6, l = threadIdx.x & 63;
    int lr = l & 15, lg = l >> 4;
    int base = blockIdx.x * 128;
    const int KD = KSTEPS * 32;
    f32x4 acc0[4], acc1[4];
#pragma unroll
    for (int cf = 0; cf < 4; ++cf) { acc0[cf] = (f32x4){0,0,0,0}; acc1[cf] = (f32x4){0,0,0,0}; }
    int arow0 = base + w * 16 + lr;      if (arow0 > M - 1) arow0 = M - 1;
    int arow1 = base + 64 + w * 16 + lr; if (arow1 > M - 1) arow1 = M - 1;
#pragma unroll
    for (int step = 0; step < KSTEPS; ++step) {
        s16x8 a0 = *(const s16x8*)(A + (size_t)arow0 * KD + step * 32 + lg * 8);
        s16x8 a1 = *(const s16x8*)(A + (size_t)arow1 * KD + step * 32 + lg * 8);
#pragma unroll
        for (int cf = 0; cf < 4; ++cf) {
            int ctl = blockIdx.y * 4 + cf;
            if (ctl < zct) {
                int ctg = ct0 + ctl;
                const unsigned short* bp =
                    BF + ((((size_t)ctg * KSTEPS + step) * 4 + lg) * 16 + lr) * 8;
                s16x8 b = *(const s16x8*)bp;
                acc0[cf] = __builtin_amdgcn_mfma_f32_16x16x32_bf16(a0, b, acc0[cf], 0, 0, 0);
                acc1[cf] = __builtin_amdgcn_mfma_f32_16x16x32_bf16(a1, b, acc1[cf], 0, 0, 0);
            }
        }
    }
#pragma unroll
    for (int cf = 0; cf < 4; ++cf) {
        int colL = cf * 16 + lr;
#pragma unroll
        for (int r = 0; r < 4; ++r) {
            int rl0 = w * 16 + lg * 4 + r;
            ztile[rl0 * 72 + colL] = f2h(acc0[cf][r]);
            ztile[(rl0 + 64) * 72 + colL] = f2h(acc1[cf][r]);
        }
    }
    __syncthreads();
    int rows_in = M - base; if (rows_in > 128) rows_in = 128;
    int valid_cols = (zct - blockIdx.y * 4) * 16; if (valid_cols > 64) valid_cols = 64;
    int bcol = blockIdx.y * 64;
    for (int i = threadIdx.x; i < 128 * 8; i += 256) {
        int rl = i >> 3, cq = (i & 7) * 8;
        if (rl < rows_in && cq < valid_cols) {
            uint4 v = *(const uint4*)(ztile + rl * 72 + cq);
            *(uint4*)(Z + (size_t)(base + rl) * zld + bcol + cq) = v;
        }
    }
}

// conv1 phase A: edge-parallel (wave/edge, col-order streaming reads);
// W1 via L1 (32KB, cache-hot); scatter-store msg to row-sorted slot rs[j].
__global__ __launch_bounds__(256) void msgA1_kernel(
        const float* __restrict__ basis, const unsigned char* __restrict__ idxb,
        const int* __restrict__ rs, const float* __restrict__ W1,
        unsigned short* __restrict__ msg, int E) {
    int j = blockIdx.x * 4 + (threadIdx.x >> 6);
    if (j >= E) return;
    int l = threadIdx.x & 63;
    const float4* bp = (const float4*)(basis + (size_t)j * 8);
    float4 b0 = bp[0], b1v = bp[1];
    const uchar4* ip = (const uchar4*)(idxb + (size_t)j * 8);
    uchar4 i0 = ip[0], i1 = ip[1];
    float m = b0.x * W1[i0.x * 64 + l] + b0.y * W1[i0.y * 64 + l]
            + b0.z * W1[i0.z * 64 + l] + b0.w * W1[i0.w * 64 + l]
            + b1v.x * W1[i1.x * 64 + l] + b1v.y * W1[i1.y * 64 + l]
            + b1v.z * W1[i1.z * 64 + l] + b1v.w * W1[i1.w * 64 + l];
    msg[(size_t)rs[j] * 64 + l] = f2h(m);
}

// phase A: block stages NODES col-nodes' z rows into LDS; edges (col-sorted)
// compute msg and scatter-store to row-sorted slot rs[j].
template<int CH, int NODES>
__global__ __launch_bounds__(256) void msgA_kernel(
        const unsigned short* __restrict__ z,
        const float* __restrict__ basis, const unsigned char* __restrict__ idxb,
        const int* __restrict__ cstart, const int* __restrict__ colS,
        const int* __restrict__ rs,
        unsigned short* __restrict__ msg, int msgld, int coff, int N, int E) {
    const int ROW = 125 * CH;
    __shared__ unsigned short lds[NODES * 125 * CH];
    int n0 = blockIdx.x * NODES;
    if (n0 >= N) return;
    int rows = N - n0; if (rows > NODES) rows = NODES;
    int nv4 = rows * ROW / 8;
    const uint4* src = (const uint4*)(z + (size_t)n0 * ROW);
    uint4* dst = (uint4*)lds;
    for (int i = threadIdx.x; i < nv4; i += 256) dst[i] = src[i];
    __syncthreads();
    int estart = cstart[n0];
    int eend = (n0 + NODES < N) ? cstart[n0 + NODES] : E;
    const int NG = 256 / CH;
    int g = threadIdx.x / CH, l = threadIdx.x % CH;
    for (int j = estart + g; j < eend; j += NG) {
        int node = colS[j] - n0;
        const float4* bp = (const float4*)(basis + (size_t)j * 8);
        float4 b0 = bp[0], b1v = bp[1];
        const uchar4* ip = (const uchar4*)(idxb + (size_t)j * 8);
        uchar4 i0 = ip[0], i1 = ip[1];
        const unsigned short* zr = lds + node * ROW;
        float m = b0.x * h2f(zr[i0.x * CH + l]) + b0.y * h2f(zr[i0.y * CH + l])
                + b0.z * h2f(zr[i0.z * CH + l]) + b0.w * h2f(zr[i0.w * CH + l])
                + b1v.x * h2f(zr[i1.x * CH + l]) + b1v.y * h2f(zr[i1.y * CH + l])
                + b1v.z * h2f(zr[i1.z * CH + l]) + b1v.w * h2f(zr[i1.w * CH + l]);
        msg[(size_t)rs[j] * msgld + coff + l] = f2h(m);
    }
}

// phase B streaming, 64ch -> bf16 (mean+bias+elu). Wave per node; node's msgs
// are CONTIGUOUS rows [s0, s0+cnt): coalesced independent 128B loads.
__global__ __launch_bounds__(256) void phaseBs1_kernel(
        const unsigned short* __restrict__ msg, const int* __restrict__ rowStart,
        const int* __restrict__ histR, const float* __restrict__ bias,
        unsigned short* __restrict__ outB, int N) {
    int n = blockIdx.x * 4 + (threadIdx.x >> 6);
    if (n >= N) return;
    int l = threadIdx.x & 63;
    int s0 = rowStart[n], cnt = histR[n];
    float a = 0.0f;
    for (int i = 0; i < cnt; ++i)
        a += h2f(msg[(size_t)(s0 + i) * 64 + l]);
    float v = a / fmaxf((float)cnt, 1.0f) + bias[l];
    v = (v > 0.0f) ? v : (expf(v) - 1.0f);
    outB[(size_t)n * 64 + l] = f2b(v);
}

// phase B streaming, 64ch + fused stn3/stn4 -> tt[n*3..]. Wave per node.
__global__ __launch_bounds__(256) void phaseBs2stn_kernel(
        const unsigned short* __restrict__ msg, const int* __restrict__ rowStart,
        const int* __restrict__ histR, const float* __restrict__ b2,
        const float* __restrict__ w3, const float* __restrict__ b3,
        const float* __restrict__ w4, const float* __restrict__ b4,
        float* __restrict__ tt, int N) {
    __shared__ float sh[4][64];
    __shared__ float sh3[4][64];
    int wid = threadIdx.x >> 6, l = threadIdx.x & 63;
    int n = blockIdx.x * 4 + wid;
    if (n >= N) return;
    int s0 = rowStart[n], cnt = histR[n];
    float a = 0.0f;
    for (int i = 0; i < cnt; ++i)
        a += h2f(msg[(size_t)(s0 + i) * 64 + l]);
    float v = a / fmaxf((float)cnt, 1.0f) + b2[l];
    v = (v > 0.0f) ? v : (expf(v) - 1.0f);
    sh[wid][l] = v;
    __builtin_amdgcn_wave_barrier();
    float v3 = b3[l];
#pragma unroll
    for (int i = 0; i < 64; ++i) v3 += sh[wid][i] * w3[i * 64 + l];
    v3 = (v3 > 0.0f) ? v3 : (expf(v3) - 1.0f);
    sh3[wid][l] = v3;
    __builtin_amdgcn_wave_barrier();
    if (l < 3) {
        float tv = b4[l];
#pragma unroll
        for (int i = 0; i < 64; ++i) tv += sh3[wid][i] * w4[i * 3 + l];
        tt[(size_t)n * 3 + l] = tv;
    }
}

// phase B streaming, 32ch -> out fp32 (mean+bias). Half-wave per node.
__global__ __launch_bounds__(256) void phaseBs3_kernel(
        const unsigned short* __restrict__ msg, const int* __restrict__ rowStart,
        const int* __restrict__ histR, const float* __restrict__ bias,
        float* __restrict__ out, int N) {
    int n = blockIdx.x * 8 + (threadIdx.x >> 5);
    if (n >= N) return;
    int l = threadIdx.x & 31;
    int s0 = rowStart[n], cnt = histR[n];
    float a = 0.0f;
    for (int i = 0; i < cnt; ++i)
        a += h2f(msg[(size_t)(s0 + i) * 32 + l]);
    out[(size_t)n * 32 + l] = a / fmaxf((float)cnt, 1.0f) + bias[l];
}

// stn3 + stn4 per node (fallback path only)
__global__ __launch_bounds__(64) void stn34_kernel(
        const float* __restrict__ h2, const float* __restrict__ w3,
        const float* __restrict__ b3, const float* __restrict__ w4,
        const float* __restrict__ b4, float* __restrict__ t, int N) {
    int n = blockIdx.x;
    int o = threadIdx.x;
    __shared__ float sh[64];
    __shared__ float sh3[64];
    sh[o] = h2[n * 64 + o];
    __syncthreads();
    float v = b3[o];
#pragma unroll
    for (int i = 0; i < 64; ++i) v += sh[i] * w3[i * 64 + o];
    v = (v > 0.0f) ? v : (expf(v) - 1.0f);
    sh3[o] = v;
    __syncthreads();
    if (o < 3) {
        float tv = b4[o];
#pragma unroll
        for (int i = 0; i < 64; ++i) tv += sh3[i] * w4[i * 3 + o];
        t[n * 3 + o] = tv;
    }
}

// ---- minimal fallback (only if ws is tiny; direct, correct) ----
__global__ __launch_bounds__(256) void conv1_at_kernel(
        const float* __restrict__ basis, const unsigned char* __restrict__ idxb,
        const int* __restrict__ row, const float* __restrict__ W1,
        float* __restrict__ acc, int E) {
    int j = blockIdx.x * 4 + (threadIdx.x >> 6);
    if (j >= E) return;
    int l = threadIdx.x & 63;
    float m = 0.0f;
#pragma unroll
    for (int s = 0; s < 8; ++s) m += basis[(size_t)j * 8 + s] * W1[idxb[(size_t)j * 8 + s] * 64 + l];
    atomicAdd(&acc[(size_t)row[j] * 64 + l], m);
}

__global__ __launch_bounds__(256) void conv2f_kernel(
        const float* __restrict__ h1, const float* __restrict__ basis,
        const unsigned char* __restrict__ idxb, const int* __restrict__ row,
        const int* __restrict__ col, const float* __restrict__ W2,
        float* __restrict__ acc, int E) {
    int wid = threadIdx.x >> 6;
    int lane = threadIdx.x & 63;
    int e = blockIdx.x * 4 + wid;
    __shared__ float sh[4][64];
    bool active = (e < E);
    int c = active ? col[e] : 0;
    if (active) sh[wid][lane] = h1[(size_t)c * 64 + lane];
    __syncthreads();
    if (!active) return;
    float m = 0.0f;
#pragma unroll
    for (int s = 0; s < 8; ++s) {
        const float* Wk = W2 + (size_t)idxb[(size_t)e * 8 + s] * 4096;
        float ms = 0.0f;
#pragma unroll
        for (int i = 0; i < 64; ++i) ms += sh[wid][i] * Wk[i * 64 + lane];
        m += basis[(size_t)e * 8 + s] * ms;
    }
    atomicAdd(&acc[(size_t)row[e] * 64 + lane], m);
}

__global__ __launch_bounds__(256) void conv3f_kernel(
        const float* __restrict__ x, const float* __restrict__ basis,
        const unsigned char* __restrict__ idxb, const int* __restrict__ row,
        const int* __restrict__ col, const float* __restrict__ Wc,
        float* __restrict__ acc, int E) {
    int wid = threadIdx.x >> 6;
    int lane = threadIdx.x & 63;
    int e = blockIdx.x * 4 + wid;
    __shared__ float sx[4][32];
    bool active = (e < E);
    int c = active ? col[e] : 0;
    if (active && lane < 32) sx[wid][lane] = x[(size_t)c * 32 + lane];
    __syncthreads();
    int half = lane >> 5;
    int o = lane & 31;
    float m = 0.0f;
    if (active) {
#pragma unroll
        for (int s2 = 0; s2 < 4; ++s2) {
            int s = half * 4 + s2;
            const float* Wk = Wc + (size_t)idxb[(size_t)e * 8 + s] * 1024;
            float ms = 0.0f;
#pragma unroll
            for (int i = 0; i < 32; ++i) ms += sx[wid][i] * Wk[i * 32 + o];
            m += basis[(size_t)e * 8 + s] * ms;
        }
    }
    m += __shfl_xor(m, 32);
    if (active && lane < 32) atomicAdd(&acc[(size_t)row[e] * 32 + o], m);
}

__global__ void finalize_kernel(const float* __restrict__ acc, const int* __restrict__ histR,
                                const float* __restrict__ bias, float* __restrict__ outF,
                                unsigned short* __restrict__ outB,
                                int N, int F, int do_elu) {
    int t = blockIdx.x * blockDim.x + threadIdx.x;
    if (t >= N * F) return;
    int n = t / F, o = t % F;
    float v = acc[t] / fmaxf((float)histR[n], 1.0f) + bias[o];
    if (do_elu) v = (v > 0.0f) ? v : (expf(v) - 1.0f);
    if (outF) outF[t] = v;
    if (outB) outB[t] = f2b(v);
}

extern "C" void kernel_launch(void* const* d_in, const int* in_sizes, int n_in,
                              void* d_out, int out_size, void* d_ws, size_t ws_size,
                              hipStream_t stream) {
    const float* x      = (const float*)d_in[0];
    const int*   ei     = (const int*)d_in[1];
    const float* pseudo = (const float*)d_in[2];
    const float* w1     = (const float*)d_in[3];
    const float* b1     = (const float*)d_in[4];
    const float* w2     = (const float*)d_in[5];
    const float* b2     = (const float*)d_in[6];
    const float* w3     = (const float*)d_in[7];
    const float* b3     = (const float*)d_in[8];
    const float* w4     = (const float*)d_in[9];
    const float* b4     = (const float*)d_in[10];
    const float* wc     = (const float*)d_in[11];
    const float* cb     = (const float*)d_in[12];
    float* out = (float*)d_out;

    const int N = in_sizes[0] / 32;
    const int E = in_sizes[1] / 2;
    const int* row = ei;
    const int* col = ei + E;
    const int KC = 125;
    const int CH = 32;

    char* p = (char*)d_ws;
    // zeroed: histograms
    int* histR = (int*)p; p += (size_t)N * sizeof(int);
    int* histC = (int*)p; p += (size_t)N * sizeof(int);
    size_t zero_bytes = (size_t)(p - (char*)d_ws);
    // non-zeroed
    int* cstart   = (int*)p; p += (size_t)N * sizeof(int);
    int* cursorC  = (int*)p; p += (size_t)N * sizeof(int);
    int* rowStart = (int*)p; p += (size_t)N * sizeof(int);
    int* cursorR  = (int*)p; p += (size_t)N * sizeof(int);
    int* jpos = (int*)p; p += (size_t)E * sizeof(int);
    int* colS = (int*)p; p += (size_t)E * sizeof(int);
    int* rs   = (int*)p; p += (size_t)E * sizeof(int);
    float* tt = (float*)p; p += (size_t)N * 3 * sizeof(float);
    float* basis = (float*)p; p += (size_t)E * 8 * sizeof(float);
    unsigned char* idxb = (unsigned char*)p; p += (size_t)E * 8;
    unsigned short* h1b = (unsigned short*)p; p += (size_t)N * 64 * sizeof(short);
    unsigned short* xb  = (unsigned short*)p; p += (size_t)N * 32 * sizeof(short);
    unsigned short* BF2 = (unsigned short*)p; p += (size_t)KC * 64 * 64 * sizeof(short);
    unsigned short* BF3 = (unsigned short*)p; p += (size_t)KC * 32 * 32 * sizeof(short);
    unsigned short* msg = (unsigned short*)p; p += (size_t)E * 64 * sizeof(short);
    size_t fixed = (size_t)(p - (char*)d_ws);
    size_t zcap = (ws_size > fixed) ? (ws_size - fixed) : 0;
    unsigned short* zbuf = (unsigned short*)p;

    const size_t z_chunk = (size_t)N * KC * CH * sizeof(short);  // 160MB
    bool fast = zcap >= z_chunk;

    hipMemsetAsync(d_ws, 0, zero_bytes, stream);
    hist_kernel<<<(E + 255) / 256, 256, 0, stream>>>(row, col, histR, histC, E);

    const int MT128 = (N + 127) / 128;

    if (fast) {
        const int H2 = 64 / CH;        // 2 splits for conv2
        const int zld = KC * CH;       // 4000
        const int zct = KC * CH / 16;  // 250 col-tiles per split

        pack_w_kernel<<<(KC * 64 * 64 + 255) / 256, 256, 0, stream>>>(w2, BF2, KC, 64, 64, 2, CH);
        pack_w_kernel<<<(KC * 32 * 32 + 255) / 256, 256, 0, stream>>>(wc, BF3, KC, 32, 32, 1, CH);
        castbf_kernel<<<(N * 32 + 255) / 256, 256, 0, stream>>>(x, xb, N * 32);

        scan_kernel<<<1, 1024, 0, stream>>>(histC, cstart, cursorC, N);
        scan_kernel<<<1, 1024, 0, stream>>>(histR, rowStart, cursorR, N);
        scatter_kernel<<<(E + 255) / 256, 256, 0, stream>>>(row, col, cursorC, cursorR,
                                                            jpos, colS, rs, E);
        basis1_kernel<<<(E + 255) / 256, 256, 0, stream>>>(pseudo, jpos, basis, idxb, E);

        // conv1: edge-parallel msg + streaming reduce
        msgA1_kernel<<<(E + 3) / 4, 256, 0, stream>>>(basis, idxb, rs, w1, msg, E);
        phaseBs1_kernel<<<(N + 3) / 4, 256, 0, stream>>>(msg, rowStart, histR, b1, h1b, N);

        // conv2: 2 channel-split z rounds
        for (int s = 0; s < H2; ++s) {
            dim3 g(MT128, (zct + 3) / 4);
            zgemm_kernel<2><<<g, 256, 0, stream>>>(h1b, N, BF2, zbuf, zld, s * zct, zct);
            msgA_kernel<32, 4><<<(N + 3) / 4, 256, 0, stream>>>(
                zbuf, basis, idxb, cstart, colS, rs, msg, 64, s * CH, N, E);
        }
        // streaming reduce + fused stn3/stn4 -> tt
        phaseBs2stn_kernel<<<(N + 3) / 4, 256, 0, stream>>>(msg, rowStart, histR, b2,
                                                            w3, b3, w4, b4, tt, N);
        basis2_kernel<<<(E + 255) / 256, 256, 0, stream>>>(pseudo, tt, row, col, jpos,
                                                           basis, idxb, E);
        // conv3: single round (CH=32 == Fout)
        {
            dim3 g(MT128, (zct + 3) / 4);
            zgemm_kernel<1><<<g, 256, 0, stream>>>(xb, N, BF3, zbuf, zld, 0, zct);
            msgA_kernel<32, 4><<<(N + 3) / 4, 256, 0, stream>>>(
                zbuf, basis, idxb, cstart, colS, rs, msg, 32, 0, N, E);
        }
        phaseBs3_kernel<<<(N + 7) / 8, 256, 0, stream>>>(msg, rowStart, histR, cb, out, N);
    } else {
        // tiny-ws fallback: direct convs with atomics (correct, slow)
        float* acc1 = (float*)msg;                 // alias into msg region
        float* acc2 = acc1 + (size_t)N * 64;
        float* acc3 = acc2 + (size_t)N * 64;
        float* h1f  = acc3 + (size_t)N * 32;
        float* h2f_ = h1f  + (size_t)N * 64;
        size_t acc_bytes = (size_t)N * (64 + 64 + 32) * sizeof(float);
        hipMemsetAsync((void*)acc1, 0, acc_bytes, stream);

        basis1_kernel<<<(E + 255) / 256, 256, 0, stream>>>(pseudo, nullptr, basis, idxb, E);
        conv1_at_kernel<<<(E + 3) / 4, 256, 0, stream>>>(basis, idxb, row, w1, acc1, E);
        finalize_kernel<<<(N * 64 + 255) / 256, 256, 0, stream>>>(acc1, histR, b1, h1f, nullptr, N, 64, 1);
        conv2f_kernel<<<(E + 3) / 4, 256, 0, stream>>>(h1f, basis, idxb, row, col, w2, acc2, E);
        finalize_kernel<<<(N * 64 + 255) / 256, 256, 0, stream>>>(acc2, histR, b2, h2f_, nullptr, N, 64, 1);
        stn34_kernel<<<N, 64, 0, stream>>>(h2f_, w3, b3, w4, b4, tt, N);
        basis2_kernel<<<(E + 255) / 256, 256, 0, stream>>>(pseudo, tt, row, col, nullptr, basis, idxb, E);
        conv3f_kernel<<<(E + 3) / 4, 256, 0, stream>>>(x, basis, idxb, row, col, wc, acc3, E);
        finalize_kernel<<<(N * 32 + 255) / 256, 256, 0, stream>>>(acc3, histR, cb, out, nullptr, N, 32, 0);
    }
}

// Round 9
// 562.881 us; speedup vs baseline: 1.0893x; 1.0153x over previous
//
#include <hip/hip_runtime.h>
#include <hip/hip_bf16.h>
#include <math.h>

// InvGraphConv: SplineCNN block on MI355X.
// N=20000, E=320000, D=3, KS=5 -> K=125, S=8, Fin=Fout=32, hidden=64.
//
// R9: z never touches HBM. fusedconv: each block owns 16 col-nodes, computes
// their z rows (16 x 2000 fp16) in LDS via MFMA (B frags L2-resident), then
// runs the edge pass from LDS, scatter-storing msg to row-sorted slots.
// Channel-splits looped in-kernel (conv2: 4x16ch, conv3: 2x16ch).
// Phase B: contiguous streaming reduce (R8). conv1: edge-parallel + reduce.

typedef short  s16x8 __attribute__((ext_vector_type(8)));
typedef float  f32x4 __attribute__((ext_vector_type(4)));

__device__ __forceinline__ unsigned short f2b(float f) {
    __hip_bfloat16 h = __float2bfloat16(f);
    return __builtin_bit_cast(unsigned short, h);
}
__device__ __forceinline__ unsigned short f2h(float f) {
    _Float16 h = (_Float16)f;
    return __builtin_bit_cast(unsigned short, h);
}
__device__ __forceinline__ float h2f(unsigned short u) {
    _Float16 h = __builtin_bit_cast(_Float16, u);
    return (float)h;
}

__device__ __forceinline__ void spline8(const float u0, const float u1, const float u2,
                                        float* __restrict__ b, int* __restrict__ id) {
    const float u[3] = {u0, u1, u2};
    const int strides[3] = {25, 5, 1};
    float fr[3];
    int   i0[3];
#pragma unroll
    for (int d = 0; d < 3; ++d) {
        float p = u[d] * 4.0f;
        float f = floorf(p);
        f = fminf(fmaxf(f, 0.0f), 3.0f);
        i0[d] = (int)f;
        fr[d] = p - f;
    }
#pragma unroll
    for (int s = 0; s < 8; ++s) {
        float bb = 1.0f;
        int   ii = 0;
#pragma unroll
        for (int d = 0; d < 3; ++d) {
            int c = (s >> d) & 1;
            bb *= c ? fr[d] : (1.0f - fr[d]);
            ii += (i0[d] + c) * strides[d];
        }
        b[s] = bb;
        id[s] = ii;
    }
}

__global__ void hist_kernel(const int* __restrict__ row, const int* __restrict__ col,
                            int* __restrict__ histR, int* __restrict__ histC, int E) {
    int e = blockIdx.x * blockDim.x + threadIdx.x;
    if (e >= E) return;
    atomicAdd(&histR[row[e]], 1);
    atomicAdd(&histC[col[e]], 1);
}

// single-block exclusive scan of hist[N] -> out1 (and optional copy out2)
__global__ __launch_bounds__(1024) void scan_kernel(const int* __restrict__ hist,
                                                    int* __restrict__ out1,
                                                    int* __restrict__ out2, int N) {
    __shared__ int wsum[16];
    __shared__ int carry;
    int t = threadIdx.x, lane = t & 63, w = t >> 6;
    if (t == 0) carry = 0;
    __syncthreads();
    for (int base = 0; base < N; base += 1024) {
        int i = base + t;
        int v = (i < N) ? hist[i] : 0;
        int sc = v;
#pragma unroll
        for (int off = 1; off < 64; off <<= 1) {
            int u = __shfl_up(sc, off);
            if (lane >= off) sc += u;
        }
        if (lane == 63) wsum[w] = sc;
        __syncthreads();
        if (w == 0 && lane < 16) {
            int s = wsum[lane];
#pragma unroll
            for (int off = 1; off < 16; off <<= 1) {
                int u = __shfl_up(s, off);
                if (lane >= off) s += u;
            }
            wsum[lane] = s;
        }
        __syncthreads();
        int woff = (w > 0 ? wsum[w - 1] : 0) + carry;
        int excl = woff + sc - v;
        if (i < N) {
            out1[i] = excl;
            if (out2) out2[i] = excl;
        }
        __syncthreads();
        if (t == 0) carry += wsum[15];
        __syncthreads();
    }
}

// dual scatter: jc = col-sorted slot, jr = row-sorted slot.
__global__ void scatter_kernel(const int* __restrict__ row, const int* __restrict__ col,
                               int* __restrict__ cursorC, int* __restrict__ cursorR,
                               int* __restrict__ jpos, int* __restrict__ colS,
                               int* __restrict__ rs, int E) {
    int e = blockIdx.x * blockDim.x + threadIdx.x;
    if (e >= E) return;
    int c = col[e], r = row[e];
    int jc = atomicAdd(&cursorC[c], 1);
    int jr = atomicAdd(&cursorR[r], 1);
    jpos[e] = jc;
    colS[jc] = c;
    rs[jc] = jr;
}

__global__ void basis1_kernel(const float* __restrict__ pseudo, const int* __restrict__ jpos,
                              float* __restrict__ basis, unsigned char* __restrict__ idxb, int E) {
    int e = blockIdx.x * blockDim.x + threadIdx.x;
    if (e >= E) return;
    float b[8]; int id[8];
    spline8(pseudo[e * 3 + 0], pseudo[e * 3 + 1], pseudo[e * 3 + 2], b, id);
    int j = jpos ? jpos[e] : e;
#pragma unroll
    for (int s = 0; s < 8; ++s) { basis[(size_t)j * 8 + s] = b[s]; idxb[(size_t)j * 8 + s] = (unsigned char)id[s]; }
}

__global__ void basis2_kernel(const float* __restrict__ pseudo, const float* __restrict__ t,
                              const int* __restrict__ row, const int* __restrict__ col,
                              const int* __restrict__ jpos,
                              float* __restrict__ basis, unsigned char* __restrict__ idxb, int E) {
    int e = blockIdx.x * blockDim.x + threadIdx.x;
    if (e >= E) return;
    int r = row[e], c = col[e];
    float u[3];
#pragma unroll
    for (int d = 0; d < 3; ++d) {
        float v = pseudo[e * 3 + d] + t[c * 3 + d] - t[r * 3 + d];
        u[d] = fminf(fmaxf(v, 0.0f), 1.0f);
    }
    float b[8]; int id[8];
    spline8(u[0], u[1], u[2], b, id);
    int j = jpos ? jpos[e] : e;
#pragma unroll
    for (int s = 0; s < 8; ++s) { basis[(size_t)j * 8 + s] = b[s]; idxb[(size_t)j * 8 + s] = (unsigned char)id[s]; }
}

__global__ void castbf_kernel(const float* __restrict__ in, unsigned short* __restrict__ out,
                              int n) {
    int t = blockIdx.x * blockDim.x + threadIdx.x;
    if (t < n) out[t] = f2b(in[t]);
}

// Pack W [Kc][Fin][Fout] fp32 -> MFMA B-fragments bf16, channel-split order:
// global col c' = (o/CH)*(Kc*CH) + k*CH + o%CH. (CH=16 here.)
__global__ void pack_w_kernel(const float* __restrict__ W, unsigned short* __restrict__ BF,
                              int Kc, int Fin, int Fout, int ksteps, int CH) {
    int t = blockIdx.x * blockDim.x + threadIdx.x;
    int total = Kc * Fout * Fin;
    if (t >= total) return;
    int c = t / Fin;
    int i = t % Fin;
    int kk = c / Fout, o = c % Fout;
    int split = o / CH;
    int cp = split * (Kc * CH) + kk * CH + (o % CH);
    int ct = cp >> 4, lr = cp & 15;
    int step = i >> 5, rem = i & 31, lg = rem >> 3, jj = rem & 7;
    size_t dst = ((((size_t)ct * ksteps + step) * 4 + lg) * 16 + lr) * 8 + jj;
    BF[dst] = f2b(W[((size_t)kk * Fin + i) * Fout + o]);
}

// conv1 phase A: edge-parallel; W1 (32KB) L1-hot; scatter msg to row slot.
__global__ __launch_bounds__(256) void msgA1_kernel(
        const float* __restrict__ basis, const unsigned char* __restrict__ idxb,
        const int* __restrict__ rs, const float* __restrict__ W1,
        unsigned short* __restrict__ msg, int E) {
    int j = blockIdx.x * 4 + (threadIdx.x >> 6);
    if (j >= E) return;
    int l = threadIdx.x & 63;
    const float4* bp = (const float4*)(basis + (size_t)j * 8);
    float4 b0 = bp[0], b1v = bp[1];
    const uchar4* ip = (const uchar4*)(idxb + (size_t)j * 8);
    uchar4 i0 = ip[0], i1 = ip[1];
    float m = b0.x * W1[i0.x * 64 + l] + b0.y * W1[i0.y * 64 + l]
            + b0.z * W1[i0.z * 64 + l] + b0.w * W1[i0.w * 64 + l]
            + b1v.x * W1[i1.x * 64 + l] + b1v.y * W1[i1.y * 64 + l]
            + b1v.z * W1[i1.z * 64 + l] + b1v.w * W1[i1.w * 64 + l];
    msg[(size_t)rs[j] * 64 + l] = f2h(m);
}

// fused zgemm+gather: block owns 16 col-nodes. Per split s:
//   MFMA: ztile[16][125*16] = A[16 rows] @ BF-slice (L2-hot), fp16 in LDS
//   edge pass: msgs for edges [cstart[n0], cstart[n0+16)) from LDS,
//              scatter-stored to row-sorted slot rs[j], channels s*16+ch.
template<int KSTEPS, int SPLITS>
__global__ __launch_bounds__(256) void fusedconv_kernel(
        const unsigned short* __restrict__ A,      // [N][KSTEPS*32] bf16
        const unsigned short* __restrict__ BF,     // packed, CH=16 split-major
        const float* __restrict__ basis, const unsigned char* __restrict__ idxb,
        const int* __restrict__ cstart, const int* __restrict__ colS,
        const int* __restrict__ rs,
        unsigned short* __restrict__ msg, int msgld, int N, int E) {
    const int ZLD = 2008;                         // padded row stride (fp16)
    __shared__ unsigned short ztile[16 * 2008];   // 64,256 B
    int n0 = blockIdx.x * 16;
    if (n0 >= N) return;
    int w = threadIdx.x >> 6, l = threadIdx.x & 63;
    int lr = l & 15, lg = l >> 4;
    const int KD = KSTEPS * 32;
    int arow = n0 + lr; if (arow > N - 1) arow = N - 1;
    s16x8 a[KSTEPS];
#pragma unroll
    for (int st = 0; st < KSTEPS; ++st)
        a[st] = *(const s16x8*)(A + (size_t)arow * KD + st * 32 + lg * 8);
    int estart = cstart[n0];
    int eend = (n0 + 16 < N) ? cstart[n0 + 16] : E;
    int g = threadIdx.x >> 4, ch = threadIdx.x & 15;
    for (int s = 0; s < SPLITS; ++s) {
        // ---- MFMA phase: wave w computes col-tiles ct = w, w+4, ... ----
        for (int ct = w; ct < 125; ct += 4) {
            f32x4 acc = (f32x4){0.f, 0.f, 0.f, 0.f};
#pragma unroll
            for (int st = 0; st < KSTEPS; ++st) {
                const unsigned short* bp =
                    BF + ((((size_t)(s * 125 + ct) * KSTEPS + st) * 4 + lg) * 16 + lr) * 8;
                s16x8 b = *(const s16x8*)bp;
                acc = __builtin_amdgcn_mfma_f32_16x16x32_bf16(a[st], b, acc, 0, 0, 0);
            }
#pragma unroll
            for (int r = 0; r < 4; ++r)
                ztile[(lg * 4 + r) * ZLD + ct * 16 + lr] = f2h(acc[r]);
        }
        __syncthreads();
        // ---- edge pass: 16 groups x 16 ch ----
        for (int j = estart + g; j < eend; j += 16) {
            int node = colS[j] - n0;
            const float4* bp = (const float4*)(basis + (size_t)j * 8);
            float4 b0 = bp[0], b1v = bp[1];
            const uchar4* ip = (const uchar4*)(idxb + (size_t)j * 8);
            uchar4 i0 = ip[0], i1 = ip[1];
            const unsigned short* zr = ztile + node * ZLD;
            float m = b0.x * h2f(zr[i0.x * 16 + ch]) + b0.y * h2f(zr[i0.y * 16 + ch])
                    + b0.z * h2f(zr[i0.z * 16 + ch]) + b0.w * h2f(zr[i0.w * 16 + ch])
                    + b1v.x * h2f(zr[i1.x * 16 + ch]) + b1v.y * h2f(zr[i1.y * 16 + ch])
                    + b1v.z * h2f(zr[i1.z * 16 + ch]) + b1v.w * h2f(zr[i1.w * 16 + ch]);
            msg[(size_t)rs[j] * msgld + s * 16 + ch] = f2h(m);
        }
        __syncthreads();
    }
}

// phase B streaming, 64ch -> bf16 (mean+bias+elu). Node's msgs contiguous.
__global__ __launch_bounds__(256) void phaseBs1_kernel(
        const unsigned short* __restrict__ msg, const int* __restrict__ rowStart,
        const int* __restrict__ histR, const float* __restrict__ bias,
        unsigned short* __restrict__ outB, int N) {
    int n = blockIdx.x * 4 + (threadIdx.x >> 6);
    if (n >= N) return;
    int l = threadIdx.x & 63;
    int s0 = rowStart[n], cnt = histR[n];
    float a = 0.0f;
    for (int i = 0; i < cnt; ++i)
        a += h2f(msg[(size_t)(s0 + i) * 64 + l]);
    float v = a / fmaxf((float)cnt, 1.0f) + bias[l];
    v = (v > 0.0f) ? v : (expf(v) - 1.0f);
    outB[(size_t)n * 64 + l] = f2b(v);
}

// phase B streaming, 64ch + fused stn3/stn4 -> tt[n*3..]. Wave per node.
__global__ __launch_bounds__(256) void phaseBs2stn_kernel(
        const unsigned short* __restrict__ msg, const int* __restrict__ rowStart,
        const int* __restrict__ histR, const float* __restrict__ b2,
        const float* __restrict__ w3, const float* __restrict__ b3,
        const float* __restrict__ w4, const float* __restrict__ b4,
        float* __restrict__ tt, int N) {
    __shared__ float sh[4][64];
    __shared__ float sh3[4][64];
    int wid = threadIdx.x >> 6, l = threadIdx.x & 63;
    int n = blockIdx.x * 4 + wid;
    if (n >= N) return;
    int s0 = rowStart[n], cnt = histR[n];
    float a = 0.0f;
    for (int i = 0; i < cnt; ++i)
        a += h2f(msg[(size_t)(s0 + i) * 64 + l]);
    float v = a / fmaxf((float)cnt, 1.0f) + b2[l];
    v = (v > 0.0f) ? v : (expf(v) - 1.0f);
    sh[wid][l] = v;
    __builtin_amdgcn_wave_barrier();
    float v3 = b3[l];
#pragma unroll
    for (int i = 0; i < 64; ++i) v3 += sh[wid][i] * w3[i * 64 + l];
    v3 = (v3 > 0.0f) ? v3 : (expf(v3) - 1.0f);
    sh3[wid][l] = v3;
    __builtin_amdgcn_wave_barrier();
    if (l < 3) {
        float tv = b4[l];
#pragma unroll
        for (int i = 0; i < 64; ++i) tv += sh3[wid][i] * w4[i * 3 + l];
        tt[(size_t)n * 3 + l] = tv;
    }
}

// phase B streaming, 32ch -> out fp32 (mean+bias). Half-wave per node.
__global__ __launch_bounds__(256) void phaseBs3_kernel(
        const unsigned short* __restrict__ msg, const int* __restrict__ rowStart,
        const int* __restrict__ histR, const float* __restrict__ bias,
        float* __restrict__ out, int N) {
    int n = blockIdx.x * 8 + (threadIdx.x >> 5);
    if (n >= N) return;
    int l = threadIdx.x & 31;
    int s0 = rowStart[n], cnt = histR[n];
    float a = 0.0f;
    for (int i = 0; i < cnt; ++i)
        a += h2f(msg[(size_t)(s0 + i) * 32 + l]);
    out[(size_t)n * 32 + l] = a / fmaxf((float)cnt, 1.0f) + bias[l];
}

// stn3 + stn4 per node (fallback path only)
__global__ __launch_bounds__(64) void stn34_kernel(
        const float* __restrict__ h2, const float* __restrict__ w3,
        const float* __restrict__ b3, const float* __restrict__ w4,
        const float* __restrict__ b4, float* __restrict__ t, int N) {
    int n = blockIdx.x;
    int o = threadIdx.x;
    __shared__ float sh[64];
    __shared__ float sh3[64];
    sh[o] = h2[n * 64 + o];
    __syncthreads();
    float v = b3[o];
#pragma unroll
    for (int i = 0; i < 64; ++i) v += sh[i] * w3[i * 64 + o];
    v = (v > 0.0f) ? v : (expf(v) - 1.0f);
    sh3[o] = v;
    __syncthreads();
    if (o < 3) {
        float tv = b4[o];
#pragma unroll
        for (int i = 0; i < 64; ++i) tv += sh3[i] * w4[i * 3 + o];
        t[n * 3 + o] = tv;
    }
}

// ---- minimal fallback (only if ws is tiny; direct, correct) ----
__global__ __launch_bounds__(256) void conv1_at_kernel(
        const float* __restrict__ basis, const unsigned char* __restrict__ idxb,
        const int* __restrict__ row, const float* __restrict__ W1,
        float* __restrict__ acc, int E) {
    int j = blockIdx.x * 4 + (threadIdx.x >> 6);
    if (j >= E) return;
    int l = threadIdx.x & 63;
    float m = 0.0f;
#pragma unroll
    for (int s = 0; s < 8; ++s) m += basis[(size_t)j * 8 + s] * W1[idxb[(size_t)j * 8 + s] * 64 + l];
    atomicAdd(&acc[(size_t)row[j] * 64 + l], m);
}

__global__ __launch_bounds__(256) void conv2f_kernel(
        const float* __restrict__ h1, const float* __restrict__ basis,
        const unsigned char* __restrict__ idxb, const int* __restrict__ row,
        const int* __restrict__ col, const float* __restrict__ W2,
        float* __restrict__ acc, int E) {
    int wid = threadIdx.x >> 6;
    int lane = threadIdx.x & 63;
    int e = blockIdx.x * 4 + wid;
    __shared__ float sh[4][64];
    bool active = (e < E);
    int c = active ? col[e] : 0;
    if (active) sh[wid][lane] = h1[(size_t)c * 64 + lane];
    __syncthreads();
    if (!active) return;
    float m = 0.0f;
#pragma unroll
    for (int s = 0; s < 8; ++s) {
        const float* Wk = W2 + (size_t)idxb[(size_t)e * 8 + s] * 4096;
        float ms = 0.0f;
#pragma unroll
        for (int i = 0; i < 64; ++i) ms += sh[wid][i] * Wk[i * 64 + lane];
        m += basis[(size_t)e * 8 + s] * ms;
    }
    atomicAdd(&acc[(size_t)row[e] * 64 + lane], m);
}

__global__ __launch_bounds__(256) void conv3f_kernel(
        const float* __restrict__ x, const float* __restrict__ basis,
        const unsigned char* __restrict__ idxb, const int* __restrict__ row,
        const int* __restrict__ col, const float* __restrict__ Wc,
        float* __restrict__ acc, int E) {
    int wid = threadIdx.x >> 6;
    int lane = threadIdx.x & 63;
    int e = blockIdx.x * 4 + wid;
    __shared__ float sx[4][32];
    bool active = (e < E);
    int c = active ? col[e] : 0;
    if (active && lane < 32) sx[wid][lane] = x[(size_t)c * 32 + lane];
    __syncthreads();
    int half = lane >> 5;
    int o = lane & 31;
    float m = 0.0f;
    if (active) {
#pragma unroll
        for (int s2 = 0; s2 < 4; ++s2) {
            int s = half * 4 + s2;
            const float* Wk = Wc + (size_t)idxb[(size_t)e * 8 + s] * 1024;
            float ms = 0.0f;
#pragma unroll
            for (int i = 0; i < 32; ++i) ms += sx[wid][i] * Wk[i * 32 + o];
            m += basis[(size_t)e * 8 + s] * ms;
        }
    }
    m += __shfl_xor(m, 32);
    if (active && lane < 32) atomicAdd(&acc[(size_t)row[e] * 32 + o], m);
}

__global__ void finalize_kernel(const float* __restrict__ acc, const int* __restrict__ histR,
                                const float* __restrict__ bias, float* __restrict__ outF,
                                unsigned short* __restrict__ outB,
                                int N, int F, int do_elu) {
    int t = blockIdx.x * blockDim.x + threadIdx.x;
    if (t >= N * F) return;
    int n = t / F, o = t % F;
    float v = acc[t] / fmaxf((float)histR[n], 1.0f) + bias[o];
    if (do_elu) v = (v > 0.0f) ? v : (expf(v) - 1.0f);
    if (outF) outF[t] = v;
    if (outB) outB[t] = f2b(v);
}

extern "C" void kernel_launch(void* const* d_in, const int* in_sizes, int n_in,
                              void* d_out, int out_size, void* d_ws, size_t ws_size,
                              hipStream_t stream) {
    const float* x      = (const float*)d_in[0];
    const int*   ei     = (const int*)d_in[1];
    const float* pseudo = (const float*)d_in[2];
    const float* w1     = (const float*)d_in[3];
    const float* b1     = (const float*)d_in[4];
    const float* w2     = (const float*)d_in[5];
    const float* b2     = (const float*)d_in[6];
    const float* w3     = (const float*)d_in[7];
    const float* b3     = (const float*)d_in[8];
    const float* w4     = (const float*)d_in[9];
    const float* b4     = (const float*)d_in[10];
    const float* wc     = (const float*)d_in[11];
    const float* cb     = (const float*)d_in[12];
    float* out = (float*)d_out;

    const int N = in_sizes[0] / 32;
    const int E = in_sizes[1] / 2;
    const int* row = ei;
    const int* col = ei + E;
    const int KC = 125;

    char* p = (char*)d_ws;
    // zeroed: histograms
    int* histR = (int*)p; p += (size_t)N * sizeof(int);
    int* histC = (int*)p; p += (size_t)N * sizeof(int);
    size_t zero_bytes = (size_t)(p - (char*)d_ws);
    // non-zeroed
    int* cstart   = (int*)p; p += (size_t)N * sizeof(int);
    int* cursorC  = (int*)p; p += (size_t)N * sizeof(int);
    int* rowStart = (int*)p; p += (size_t)N * sizeof(int);
    int* cursorR  = (int*)p; p += (size_t)N * sizeof(int);
    int* jpos = (int*)p; p += (size_t)E * sizeof(int);
    int* colS = (int*)p; p += (size_t)E * sizeof(int);
    int* rs   = (int*)p; p += (size_t)E * sizeof(int);
    float* tt = (float*)p; p += (size_t)N * 3 * sizeof(float);
    float* basis = (float*)p; p += (size_t)E * 8 * sizeof(float);
    unsigned char* idxb = (unsigned char*)p; p += (size_t)E * 8;
    unsigned short* h1b = (unsigned short*)p; p += (size_t)N * 64 * sizeof(short);
    unsigned short* xb  = (unsigned short*)p; p += (size_t)N * 32 * sizeof(short);
    unsigned short* BF2 = (unsigned short*)p; p += (size_t)KC * 64 * 64 * sizeof(short);
    unsigned short* BF3 = (unsigned short*)p; p += (size_t)KC * 32 * 32 * sizeof(short);
    unsigned short* msg = (unsigned short*)p; p += (size_t)E * 64 * sizeof(short);
    size_t fixed = (size_t)(p - (char*)d_ws);
    bool fast = ws_size >= fixed;

    hipMemsetAsync(d_ws, 0, zero_bytes, stream);
    hist_kernel<<<(E + 255) / 256, 256, 0, stream>>>(row, col, histR, histC, E);

    if (fast) {
        pack_w_kernel<<<(KC * 64 * 64 + 255) / 256, 256, 0, stream>>>(w2, BF2, KC, 64, 64, 2, 16);
        pack_w_kernel<<<(KC * 32 * 32 + 255) / 256, 256, 0, stream>>>(wc, BF3, KC, 32, 32, 1, 16);
        castbf_kernel<<<(N * 32 + 255) / 256, 256, 0, stream>>>(x, xb, N * 32);

        scan_kernel<<<1, 1024, 0, stream>>>(histC, cstart, cursorC, N);
        scan_kernel<<<1, 1024, 0, stream>>>(histR, rowStart, cursorR, N);
        scatter_kernel<<<(E + 255) / 256, 256, 0, stream>>>(row, col, cursorC, cursorR,
                                                            jpos, colS, rs, E);
        basis1_kernel<<<(E + 255) / 256, 256, 0, stream>>>(pseudo, jpos, basis, idxb, E);

        // conv1: edge-parallel msg + streaming reduce
        msgA1_kernel<<<(E + 3) / 4, 256, 0, stream>>>(basis, idxb, rs, w1, msg, E);
        phaseBs1_kernel<<<(N + 3) / 4, 256, 0, stream>>>(msg, rowStart, histR, b1, h1b, N);

        const int NB = (N + 15) / 16;
        // conv2: fused MFMA-in-LDS + gather, 4 channel-splits in-kernel
        fusedconv_kernel<2, 4><<<NB, 256, 0, stream>>>(
            h1b, BF2, basis, idxb, cstart, colS, rs, msg, 64, N, E);
        phaseBs2stn_kernel<<<(N + 3) / 4, 256, 0, stream>>>(msg, rowStart, histR, b2,
                                                            w3, b3, w4, b4, tt, N);
        basis2_kernel<<<(E + 255) / 256, 256, 0, stream>>>(pseudo, tt, row, col, jpos,
                                                           basis, idxb, E);
        // conv3: fused, 2 channel-splits in-kernel
        fusedconv_kernel<1, 2><<<NB, 256, 0, stream>>>(
            xb, BF3, basis, idxb, cstart, colS, rs, msg, 32, N, E);
        phaseBs3_kernel<<<(N + 7) / 8, 256, 0, stream>>>(msg, rowStart, histR, cb, out, N);
    } else {
        // tiny-ws fallback: direct convs with atomics (correct, slow)
        float* acc1 = (float*)msg;
        float* acc2 = acc1 + (size_t)N * 64;
        float* acc3 = acc2 + (size_t)N * 64;
        float* h1f  = acc3 + (size_t)N * 32;
        float* h2f_ = h1f  + (size_t)N * 64;
        size_t acc_bytes = (size_t)N * (64 + 64 + 32) * sizeof(float);
        hipMemsetAsync((void*)acc1, 0, acc_bytes, stream);

        basis1_kernel<<<(E + 255) / 256, 256, 0, stream>>>(pseudo, nullptr, basis, idxb, E);
        conv1_at_kernel<<<(E + 3) / 4, 256, 0, stream>>>(basis, idxb, row, w1, acc1, E);
        finalize_kernel<<<(N * 64 + 255) / 256, 256, 0, stream>>>(acc1, histR, b1, h1f, nullptr, N, 64, 1);
        conv2f_kernel<<<(E + 3) / 4, 256, 0, stream>>>(h1f, basis, idxb, row, col, w2, acc2, E);
        finalize_kernel<<<(N * 64 + 255) / 256, 256, 0, stream>>>(acc2, histR, b2, h2f_, nullptr, N, 64, 1);
        stn34_kernel<<<N, 64, 0, stream>>>(h2f_, w3, b3, w4, b4, tt, N);
        basis2_kernel<<<(E + 255) / 256, 256, 0, stream>>>(pseudo, tt, row, col, nullptr, basis, idxb, E);
        conv3f_kernel<<<(E + 3) / 4, 256, 0, stream>>>(x, basis, idxb, row, col, wc, acc3, E);
        finalize_kernel<<<(N * 32 + 255) / 256, 256, 0, stream>>>(acc3, histR, cb, out, nullptr, N, 32, 0);
    }
}

// Round 10
// 420.559 us; speedup vs baseline: 1.4580x; 1.3384x over previous
//
#include <hip/hip_runtime.h>
#include <hip/hip_bf16.h>
#include <math.h>

// InvGraphConv: SplineCNN block on MI355X.
// N=20000, E=320000, D=3, KS=5 -> K=125, S=8, Fin=Fout=32, hidden=64.
//
// R10: conv2 = fused MFMA-in-LDS (512 thr, 2 blocks/CU) with split-major msg
// planes; conv3 = unfused zgemm+msgA (proven faster); conv1 = row-sorted
// basis stream vs LDS W1 (no msg round-trip); scatter+basis fused; 1 scan.

typedef short  s16x8 __attribute__((ext_vector_type(8)));
typedef float  f32x4 __attribute__((ext_vector_type(4)));

__device__ __forceinline__ unsigned short f2b(float f) {
    __hip_bfloat16 h = __float2bfloat16(f);
    return __builtin_bit_cast(unsigned short, h);
}
__device__ __forceinline__ unsigned short f2h(float f) {
    _Float16 h = (_Float16)f;
    return __builtin_bit_cast(unsigned short, h);
}
__device__ __forceinline__ float h2f(unsigned short u) {
    _Float16 h = __builtin_bit_cast(_Float16, u);
    return (float)h;
}

__device__ __forceinline__ void spline8(const float u0, const float u1, const float u2,
                                        float* __restrict__ b, int* __restrict__ id) {
    const float u[3] = {u0, u1, u2};
    const int strides[3] = {25, 5, 1};
    float fr[3];
    int   i0[3];
#pragma unroll
    for (int d = 0; d < 3; ++d) {
        float p = u[d] * 4.0f;
        float f = floorf(p);
        f = fminf(fmaxf(f, 0.0f), 3.0f);
        i0[d] = (int)f;
        fr[d] = p - f;
    }
#pragma unroll
    for (int s = 0; s < 8; ++s) {
        float bb = 1.0f;
        int   ii = 0;
#pragma unroll
        for (int d = 0; d < 3; ++d) {
            int c = (s >> d) & 1;
            bb *= c ? fr[d] : (1.0f - fr[d]);
            ii += (i0[d] + c) * strides[d];
        }
        b[s] = bb;
        id[s] = ii;
    }
}

__global__ void hist_kernel(const int* __restrict__ row, const int* __restrict__ col,
                            int* __restrict__ histR, int* __restrict__ histC, int E) {
    int e = blockIdx.x * blockDim.x + threadIdx.x;
    if (e >= E) return;
    atomicAdd(&histR[row[e]], 1);
    atomicAdd(&histC[col[e]], 1);
}

// dual single-block exclusive scan: histC -> {cstart,cursorC}, histR -> {rowStart,cursorR}
__global__ __launch_bounds__(1024) void scan2_kernel(
        const int* __restrict__ histC, const int* __restrict__ histR,
        int* __restrict__ cstart, int* __restrict__ cursorC,
        int* __restrict__ rowStart, int* __restrict__ cursorR, int N) {
    __shared__ int wsX[16], wsY[16];
    __shared__ int carX, carY;
    int t = threadIdx.x, lane = t & 63, w = t >> 6;
    if (t == 0) { carX = 0; carY = 0; }
    __syncthreads();
    for (int base = 0; base < N; base += 1024) {
        int i = base + t;
        int vx = (i < N) ? histC[i] : 0;
        int vy = (i < N) ? histR[i] : 0;
        int sx = vx, sy = vy;
#pragma unroll
        for (int off = 1; off < 64; off <<= 1) {
            int ux = __shfl_up(sx, off);
            int uy = __shfl_up(sy, off);
            if (lane >= off) { sx += ux; sy += uy; }
        }
        if (lane == 63) { wsX[w] = sx; wsY[w] = sy; }
        __syncthreads();
        if (w == 0 && lane < 16) {
            int ax = wsX[lane], ay = wsY[lane];
#pragma unroll
            for (int off = 1; off < 16; off <<= 1) {
                int ux = __shfl_up(ax, off);
                int uy = __shfl_up(ay, off);
                if (lane >= off) { ax += ux; ay += uy; }
            }
            wsX[lane] = ax; wsY[lane] = ay;
        }
        __syncthreads();
        int wx = (w > 0 ? wsX[w - 1] : 0) + carX;
        int wy = (w > 0 ? wsY[w - 1] : 0) + carY;
        if (i < N) {
            int ex = wx + sx - vx;
            int ey = wy + sy - vy;
            cstart[i] = ex; cursorC[i] = ex;
            rowStart[i] = ey; cursorR[i] = ey;
        }
        __syncthreads();
        if (t == 0) { carX += wsX[15]; carY += wsY[15]; }
        __syncthreads();
    }
}

// fused scatter + spline basis: writes col-sorted basis/idx (for msgA/fused)
// AND row-sorted basisR/idxR (for conv1 phase B); jpos kept for basis2.
__global__ void scatterbasis_kernel(
        const int* __restrict__ row, const int* __restrict__ col,
        const float* __restrict__ pseudo,
        int* __restrict__ cursorC, int* __restrict__ cursorR,
        int* __restrict__ jpos, int* __restrict__ colS, int* __restrict__ rs,
        float* __restrict__ basis, unsigned char* __restrict__ idxb,
        float* __restrict__ basisR, unsigned char* __restrict__ idxR, int E) {
    int e = blockIdx.x * blockDim.x + threadIdx.x;
    if (e >= E) return;
    int c = col[e], r = row[e];
    int jc = atomicAdd(&cursorC[c], 1);
    int jr = atomicAdd(&cursorR[r], 1);
    jpos[e] = jc;
    colS[jc] = c;
    rs[jc] = jr;
    float b[8]; int id[8];
    spline8(pseudo[e * 3 + 0], pseudo[e * 3 + 1], pseudo[e * 3 + 2], b, id);
#pragma unroll
    for (int s = 0; s < 8; ++s) {
        basis[(size_t)jc * 8 + s] = b[s];
        idxb[(size_t)jc * 8 + s] = (unsigned char)id[s];
        basisR[(size_t)jr * 8 + s] = b[s];
        idxR[(size_t)jr * 8 + s] = (unsigned char)id[s];
    }
}

__global__ void basis1_kernel(const float* __restrict__ pseudo, const int* __restrict__ jpos,
                              float* __restrict__ basis, unsigned char* __restrict__ idxb, int E) {
    int e = blockIdx.x * blockDim.x + threadIdx.x;
    if (e >= E) return;
    float b[8]; int id[8];
    spline8(pseudo[e * 3 + 0], pseudo[e * 3 + 1], pseudo[e * 3 + 2], b, id);
    int j = jpos ? jpos[e] : e;
#pragma unroll
    for (int s = 0; s < 8; ++s) { basis[(size_t)j * 8 + s] = b[s]; idxb[(size_t)j * 8 + s] = (unsigned char)id[s]; }
}

__global__ void basis2_kernel(const float* __restrict__ pseudo, const float* __restrict__ t,
                              const int* __restrict__ row, const int* __restrict__ col,
                              const int* __restrict__ jpos,
                              float* __restrict__ basis, unsigned char* __restrict__ idxb, int E) {
    int e = blockIdx.x * blockDim.x + threadIdx.x;
    if (e >= E) return;
    int r = row[e], c = col[e];
    float u[3];
#pragma unroll
    for (int d = 0; d < 3; ++d) {
        float v = pseudo[e * 3 + d] + t[c * 3 + d] - t[r * 3 + d];
        u[d] = fminf(fmaxf(v, 0.0f), 1.0f);
    }
    float b[8]; int id[8];
    spline8(u[0], u[1], u[2], b, id);
    int j = jpos ? jpos[e] : e;
#pragma unroll
    for (int s = 0; s < 8; ++s) { basis[(size_t)j * 8 + s] = b[s]; idxb[(size_t)j * 8 + s] = (unsigned char)id[s]; }
}

__global__ void castbf_kernel(const float* __restrict__ in, unsigned short* __restrict__ out,
                              int n) {
    int t = blockIdx.x * blockDim.x + threadIdx.x;
    if (t < n) out[t] = f2b(in[t]);
}

// Pack W [Kc][Fin][Fout] fp32 -> MFMA B-fragments bf16, channel-split order.
__global__ void pack_w_kernel(const float* __restrict__ W, unsigned short* __restrict__ BF,
                              int Kc, int Fin, int Fout, int ksteps, int CH) {
    int t = blockIdx.x * blockDim.x + threadIdx.x;
    int total = Kc * Fout * Fin;
    if (t >= total) return;
    int c = t / Fin;
    int i = t % Fin;
    int kk = c / Fout, o = c % Fout;
    int split = o / CH;
    int cp = split * (Kc * CH) + kk * CH + (o % CH);
    int ct = cp >> 4, lr = cp & 15;
    int step = i >> 5, rem = i & 31, lg = rem >> 3, jj = rem & 7;
    size_t dst = ((((size_t)ct * ksteps + step) * 4 + lg) * 16 + lr) * 8 + jj;
    BF[dst] = f2b(W[((size_t)kk * Fin + i) * Fout + o]);
}

// conv1 phase B: W1 (32KB fp32) in LDS; wave per row-node; streams row-sorted
// basisR/idxR contiguously; fused mean+bias+elu -> h1 bf16.
__global__ __launch_bounds__(256) void phaseB1s_kernel(
        const float* __restrict__ W1, const float* __restrict__ basisR,
        const unsigned char* __restrict__ idxR, const int* __restrict__ rowStart,
        const int* __restrict__ histR, const float* __restrict__ b1,
        unsigned short* __restrict__ h1b, int N) {
    __shared__ float w[125 * 64];
    for (int i = threadIdx.x; i < 125 * 64; i += 256) w[i] = W1[i];
    __syncthreads();
    int n = blockIdx.x * 4 + (threadIdx.x >> 6);
    if (n >= N) return;
    int l = threadIdx.x & 63;
    int s0 = rowStart[n], cnt = histR[n];
    float a = 0.0f;
    for (int i = 0; i < cnt; ++i) {
        const float4* bp = (const float4*)(basisR + (size_t)(s0 + i) * 8);
        float4 b0 = bp[0], b1v = bp[1];
        const uchar4* ip = (const uchar4*)(idxR + (size_t)(s0 + i) * 8);
        uchar4 i0 = ip[0], i1 = ip[1];
        a += b0.x * w[i0.x * 64 + l] + b0.y * w[i0.y * 64 + l]
           + b0.z * w[i0.z * 64 + l] + b0.w * w[i0.w * 64 + l]
           + b1v.x * w[i1.x * 64 + l] + b1v.y * w[i1.y * 64 + l]
           + b1v.z * w[i1.z * 64 + l] + b1v.w * w[i1.w * 64 + l];
    }
    float v = a / fmaxf((float)cnt, 1.0f) + b1[l];
    v = (v > 0.0f) ? v : (expf(v) - 1.0f);
    h1b[(size_t)n * 64 + l] = f2b(v);
}

// fused conv2: 512 threads. Block owns 16 col-nodes. Per split s (CH=16):
// MFMA phase fills ztile[16][2000] (8 waves share 125 col-tiles), edge pass
// (32 groups x 16 ch) computes msgs from LDS, stores to split-major plane
// msgP[s][E][16] at row-sorted slot rs[j].
template<int KSTEPS, int SPLITS>
__global__ __launch_bounds__(512) void fusedconv_kernel(
        const unsigned short* __restrict__ A,
        const unsigned short* __restrict__ BF,
        const float* __restrict__ basis, const unsigned char* __restrict__ idxb,
        const int* __restrict__ cstart, const int* __restrict__ colS,
        const int* __restrict__ rs,
        unsigned short* __restrict__ msgP, int N, int E) {
    const int ZLD = 2008;
    __shared__ unsigned short ztile[16 * 2008];   // 64,256 B
    int n0 = blockIdx.x * 16;
    if (n0 >= N) return;
    int w = threadIdx.x >> 6, l = threadIdx.x & 63;
    int lr = l & 15, lg = l >> 4;
    const int KD = KSTEPS * 32;
    int arow = n0 + lr; if (arow > N - 1) arow = N - 1;
    s16x8 a[KSTEPS];
#pragma unroll
    for (int st = 0; st < KSTEPS; ++st)
        a[st] = *(const s16x8*)(A + (size_t)arow * KD + st * 32 + lg * 8);
    int estart = cstart[n0];
    int eend = (n0 + 16 < N) ? cstart[n0 + 16] : E;
    int g = threadIdx.x >> 4, ch = threadIdx.x & 15;   // 32 groups x 16 ch
    for (int s = 0; s < SPLITS; ++s) {
        for (int ct = w; ct < 125; ct += 8) {
            f32x4 acc = (f32x4){0.f, 0.f, 0.f, 0.f};
#pragma unroll
            for (int st = 0; st < KSTEPS; ++st) {
                const unsigned short* bp =
                    BF + ((((size_t)(s * 125 + ct) * KSTEPS + st) * 4 + lg) * 16 + lr) * 8;
                s16x8 b = *(const s16x8*)bp;
                acc = __builtin_amdgcn_mfma_f32_16x16x32_bf16(a[st], b, acc, 0, 0, 0);
            }
#pragma unroll
            for (int r = 0; r < 4; ++r)
                ztile[(lg * 4 + r) * ZLD + ct * 16 + lr] = f2h(acc[r]);
        }
        __syncthreads();
        unsigned short* mp = msgP + (size_t)s * E * 16;
        for (int j = estart + g; j < eend; j += 32) {
            int node = colS[j] - n0;
            const float4* bp = (const float4*)(basis + (size_t)j * 8);
            float4 b0 = bp[0], b1v = bp[1];
            const uchar4* ip = (const uchar4*)(idxb + (size_t)j * 8);
            uchar4 i0 = ip[0], i1 = ip[1];
            const unsigned short* zr = ztile + node * ZLD;
            float m = b0.x * h2f(zr[i0.x * 16 + ch]) + b0.y * h2f(zr[i0.y * 16 + ch])
                    + b0.z * h2f(zr[i0.z * 16 + ch]) + b0.w * h2f(zr[i0.w * 16 + ch])
                    + b1v.x * h2f(zr[i1.x * 16 + ch]) + b1v.y * h2f(zr[i1.y * 16 + ch])
                    + b1v.z * h2f(zr[i1.z * 16 + ch]) + b1v.w * h2f(zr[i1.w * 16 + ch]);
            mp[(size_t)rs[j] * 16 + ch] = f2h(m);
        }
        __syncthreads();
    }
}

// z = A @ B via mfma -> fp16 Z [M][zld]; LDS-bounce epilogue (stride 72).
template<int KSTEPS>
__global__ __launch_bounds__(256) void zgemm_kernel(
        const unsigned short* __restrict__ A, int M,
        const unsigned short* __restrict__ BF,
        unsigned short* __restrict__ Z, int zld, int ct0, int zct) {
    __shared__ unsigned short ztile[128 * 72];
    int w = threadIdx.x >> 6, l = threadIdx.x & 63;
    int lr = l & 15, lg = l >> 4;
    int base = blockIdx.x * 128;
    const int KD = KSTEPS * 32;
    f32x4 acc0[4], acc1[4];
#pragma unroll
    for (int cf = 0; cf < 4; ++cf) { acc0[cf] = (f32x4){0,0,0,0}; acc1[cf] = (f32x4){0,0,0,0}; }
    int arow0 = base + w * 16 + lr;      if (arow0 > M - 1) arow0 = M - 1;
    int arow1 = base + 64 + w * 16 + lr; if (arow1 > M - 1) arow1 = M - 1;
#pragma unroll
    for (int step = 0; step < KSTEPS; ++step) {
        s16x8 a0 = *(const s16x8*)(A + (size_t)arow0 * KD + step * 32 + lg * 8);
        s16x8 a1 = *(const s16x8*)(A + (size_t)arow1 * KD + step * 32 + lg * 8);
#pragma unroll
        for (int cf = 0; cf < 4; ++cf) {
            int ctl = blockIdx.y * 4 + cf;
            if (ctl < zct) {
                int ctg = ct0 + ctl;
                const unsigned short* bp =
                    BF + ((((size_t)ctg * KSTEPS + step) * 4 + lg) * 16 + lr) * 8;
                s16x8 b = *(const s16x8*)bp;
                acc0[cf] = __builtin_amdgcn_mfma_f32_16x16x32_bf16(a0, b, acc0[cf], 0, 0, 0);
                acc1[cf] = __builtin_amdgcn_mfma_f32_16x16x32_bf16(a1, b, acc1[cf], 0, 0, 0);
            }
        }
    }
#pragma unroll
    for (int cf = 0; cf < 4; ++cf) {
        int colL = cf * 16 + lr;
#pragma unroll
        for (int r = 0; r < 4; ++r) {
            int rl0 = w * 16 + lg * 4 + r;
            ztile[rl0 * 72 + colL] = f2h(acc0[cf][r]);
            ztile[(rl0 + 64) * 72 + colL] = f2h(acc1[cf][r]);
        }
    }
    __syncthreads();
    int rows_in = M - base; if (rows_in > 128) rows_in = 128;
    int valid_cols = (zct - blockIdx.y * 4) * 16; if (valid_cols > 64) valid_cols = 64;
    int bcol = blockIdx.y * 64;
    for (int i = threadIdx.x; i < 128 * 8; i += 256) {
        int rl = i >> 3, cq = (i & 7) * 8;
        if (rl < rows_in && cq < valid_cols) {
            uint4 v = *(const uint4*)(ztile + rl * 72 + cq);
            *(uint4*)(Z + (size_t)(base + rl) * zld + bcol + cq) = v;
        }
    }
}

// conv3 phase A: stage 4 col-nodes' z rows (125*32 fp16) in LDS; edges
// scatter-store 64B msg to row-sorted slot.
template<int CH, int NODES>
__global__ __launch_bounds__(256) void msgA_kernel(
        const unsigned short* __restrict__ z,
        const float* __restrict__ basis, const unsigned char* __restrict__ idxb,
        const int* __restrict__ cstart, const int* __restrict__ colS,
        const int* __restrict__ rs,
        unsigned short* __restrict__ msg, int msgld, int coff, int N, int E) {
    const int ROW = 125 * CH;
    __shared__ unsigned short lds[NODES * 125 * CH];
    int n0 = blockIdx.x * NODES;
    if (n0 >= N) return;
    int rows = N - n0; if (rows > NODES) rows = NODES;
    int nv4 = rows * ROW / 8;
    const uint4* src = (const uint4*)(z + (size_t)n0 * ROW);
    uint4* dst = (uint4*)lds;
    for (int i = threadIdx.x; i < nv4; i += 256) dst[i] = src[i];
    __syncthreads();
    int estart = cstart[n0];
    int eend = (n0 + NODES < N) ? cstart[n0 + NODES] : E;
    const int NG = 256 / CH;
    int g = threadIdx.x / CH, l = threadIdx.x % CH;
    for (int j = estart + g; j < eend; j += NG) {
        int node = colS[j] - n0;
        const float4* bp = (const float4*)(basis + (size_t)j * 8);
        float4 b0 = bp[0], b1v = bp[1];
        const uchar4* ip = (const uchar4*)(idxb + (size_t)j * 8);
        uchar4 i0 = ip[0], i1 = ip[1];
        const unsigned short* zr = lds + node * ROW;
        float m = b0.x * h2f(zr[i0.x * CH + l]) + b0.y * h2f(zr[i0.y * CH + l])
                + b0.z * h2f(zr[i0.z * CH + l]) + b0.w * h2f(zr[i0.w * CH + l])
                + b1v.x * h2f(zr[i1.x * CH + l]) + b1v.y * h2f(zr[i1.y * CH + l])
                + b1v.z * h2f(zr[i1.z * CH + l]) + b1v.w * h2f(zr[i1.w * CH + l]);
        msg[(size_t)rs[j] * msgld + coff + l] = f2h(m);
    }
}

// phase B conv2 + fused stn3/stn4 -> tt. Reads 4 split-major msg planes.
__global__ __launch_bounds__(256) void phaseBs2stn_kernel(
        const unsigned short* __restrict__ msgP, const int* __restrict__ rowStart,
        const int* __restrict__ histR, const float* __restrict__ b2,
        const float* __restrict__ w3, const float* __restrict__ b3,
        const float* __restrict__ w4, const float* __restrict__ b4,
        float* __restrict__ tt, int N, int E) {
    __shared__ float sh[4][64];
    __shared__ float sh3[4][64];
    int wid = threadIdx.x >> 6, l = threadIdx.x & 63;
    int n = blockIdx.x * 4 + wid;
    if (n >= N) return;
    int s0 = rowStart[n], cnt = histR[n];
    const unsigned short* mp = msgP + (size_t)(l >> 4) * E * 16 + (l & 15);
    float a = 0.0f;
    for (int i = 0; i < cnt; ++i)
        a += h2f(mp[(size_t)(s0 + i) * 16]);
    float v = a / fmaxf((float)cnt, 1.0f) + b2[l];
    v = (v > 0.0f) ? v : (expf(v) - 1.0f);
    sh[wid][l] = v;
    __builtin_amdgcn_wave_barrier();
    float v3 = b3[l];
#pragma unroll
    for (int i = 0; i < 64; ++i) v3 += sh[wid][i] * w3[i * 64 + l];
    v3 = (v3 > 0.0f) ? v3 : (expf(v3) - 1.0f);
    sh3[wid][l] = v3;
    __builtin_amdgcn_wave_barrier();
    if (l < 3) {
        float tv = b4[l];
#pragma unroll
        for (int i = 0; i < 64; ++i) tv += sh3[wid][i] * w4[i * 3 + l];
        tt[(size_t)n * 3 + l] = tv;
    }
}

// phase B conv3: half-wave per node; contiguous msg rows; mean+bias -> out.
__global__ __launch_bounds__(256) void phaseBs3_kernel(
        const unsigned short* __restrict__ msg, const int* __restrict__ rowStart,
        const int* __restrict__ histR, const float* __restrict__ bias,
        float* __restrict__ out, int N) {
    int n = blockIdx.x * 8 + (threadIdx.x >> 5);
    if (n >= N) return;
    int l = threadIdx.x & 31;
    int s0 = rowStart[n], cnt = histR[n];
    float a = 0.0f;
    for (int i = 0; i < cnt; ++i)
        a += h2f(msg[(size_t)(s0 + i) * 32 + l]);
    out[(size_t)n * 32 + l] = a / fmaxf((float)cnt, 1.0f) + bias[l];
}

// stn3 + stn4 per node (fallback path only)
__global__ __launch_bounds__(64) void stn34_kernel(
        const float* __restrict__ h2, const float* __restrict__ w3,
        const float* __restrict__ b3, const float* __restrict__ w4,
        const float* __restrict__ b4, float* __restrict__ t, int N) {
    int n = blockIdx.x;
    int o = threadIdx.x;
    __shared__ float sh[64];
    __shared__ float sh3[64];
    sh[o] = h2[n * 64 + o];
    __syncthreads();
    float v = b3[o];
#pragma unroll
    for (int i = 0; i < 64; ++i) v += sh[i] * w3[i * 64 + o];
    v = (v > 0.0f) ? v : (expf(v) - 1.0f);
    sh3[o] = v;
    __syncthreads();
    if (o < 3) {
        float tv = b4[o];
#pragma unroll
        for (int i = 0; i < 64; ++i) tv += sh3[i] * w4[i * 3 + o];
        t[n * 3 + o] = tv;
    }
}

// ---- minimal fallback (only if ws is tiny; direct, correct) ----
__global__ __launch_bounds__(256) void conv1_at_kernel(
        const float* __restrict__ basis, const unsigned char* __restrict__ idxb,
        const int* __restrict__ row, const float* __restrict__ W1,
        float* __restrict__ acc, int E) {
    int j = blockIdx.x * 4 + (threadIdx.x >> 6);
    if (j >= E) return;
    int l = threadIdx.x & 63;
    float m = 0.0f;
#pragma unroll
    for (int s = 0; s < 8; ++s) m += basis[(size_t)j * 8 + s] * W1[idxb[(size_t)j * 8 + s] * 64 + l];
    atomicAdd(&acc[(size_t)row[j] * 64 + l], m);
}

__global__ __launch_bounds__(256) void conv2f_kernel(
        const float* __restrict__ h1, const float* __restrict__ basis,
        const unsigned char* __restrict__ idxb, const int* __restrict__ row,
        const int* __restrict__ col, const float* __restrict__ W2,
        float* __restrict__ acc, int E) {
    int wid = threadIdx.x >> 6;
    int lane = threadIdx.x & 63;
    int e = blockIdx.x * 4 + wid;
    __shared__ float sh[4][64];
    bool active = (e < E);
    int c = active ? col[e] : 0;
    if (active) sh[wid][lane] = h1[(size_t)c * 64 + lane];
    __syncthreads();
    if (!active) return;
    float m = 0.0f;
#pragma unroll
    for (int s = 0; s < 8; ++s) {
        const float* Wk = W2 + (size_t)idxb[(size_t)e * 8 + s] * 4096;
        float ms = 0.0f;
#pragma unroll
        for (int i = 0; i < 64; ++i) ms += sh[wid][i] * Wk[i * 64 + lane];
        m += basis[(size_t)e * 8 + s] * ms;
    }
    atomicAdd(&acc[(size_t)row[e] * 64 + lane], m);
}

__global__ __launch_bounds__(256) void conv3f_kernel(
        const float* __restrict__ x, const float* __restrict__ basis,
        const unsigned char* __restrict__ idxb, const int* __restrict__ row,
        const int* __restrict__ col, const float* __restrict__ Wc,
        float* __restrict__ acc, int E) {
    int wid = threadIdx.x >> 6;
    int lane = threadIdx.x & 63;
    int e = blockIdx.x * 4 + wid;
    __shared__ float sx[4][32];
    bool active = (e < E);
    int c = active ? col[e] : 0;
    if (active && lane < 32) sx[wid][lane] = x[(size_t)c * 32 + lane];
    __syncthreads();
    int half = lane >> 5;
    int o = lane & 31;
    float m = 0.0f;
    if (active) {
#pragma unroll
        for (int s2 = 0; s2 < 4; ++s2) {
            int s = half * 4 + s2;
            const float* Wk = Wc + (size_t)idxb[(size_t)e * 8 + s] * 1024;
            float ms = 0.0f;
#pragma unroll
            for (int i = 0; i < 32; ++i) ms += sx[wid][i] * Wk[i * 32 + o];
            m += basis[(size_t)e * 8 + s] * ms;
        }
    }
    m += __shfl_xor(m, 32);
    if (active && lane < 32) atomicAdd(&acc[(size_t)row[e] * 32 + o], m);
}

__global__ void finalize_kernel(const float* __restrict__ acc, const int* __restrict__ histR,
                                const float* __restrict__ bias, float* __restrict__ outF,
                                unsigned short* __restrict__ outB,
                                int N, int F, int do_elu) {
    int t = blockIdx.x * blockDim.x + threadIdx.x;
    if (t >= N * F) return;
    int n = t / F, o = t % F;
    float v = acc[t] / fmaxf((float)histR[n], 1.0f) + bias[o];
    if (do_elu) v = (v > 0.0f) ? v : (expf(v) - 1.0f);
    if (outF) outF[t] = v;
    if (outB) outB[t] = f2b(v);
}

extern "C" void kernel_launch(void* const* d_in, const int* in_sizes, int n_in,
                              void* d_out, int out_size, void* d_ws, size_t ws_size,
                              hipStream_t stream) {
    const float* x      = (const float*)d_in[0];
    const int*   ei     = (const int*)d_in[1];
    const float* pseudo = (const float*)d_in[2];
    const float* w1     = (const float*)d_in[3];
    const float* b1     = (const float*)d_in[4];
    const float* w2     = (const float*)d_in[5];
    const float* b2     = (const float*)d_in[6];
    const float* w3     = (const float*)d_in[7];
    const float* b3     = (const float*)d_in[8];
    const float* w4     = (const float*)d_in[9];
    const float* b4     = (const float*)d_in[10];
    const float* wc     = (const float*)d_in[11];
    const float* cb     = (const float*)d_in[12];
    float* out = (float*)d_out;

    const int N = in_sizes[0] / 32;
    const int E = in_sizes[1] / 2;
    const int* row = ei;
    const int* col = ei + E;
    const int KC = 125;

    char* p = (char*)d_ws;
    // zeroed: histograms
    int* histR = (int*)p; p += (size_t)N * sizeof(int);
    int* histC = (int*)p; p += (size_t)N * sizeof(int);
    size_t zero_bytes = (size_t)(p - (char*)d_ws);
    // non-zeroed
    int* cstart   = (int*)p; p += (size_t)N * sizeof(int);
    int* cursorC  = (int*)p; p += (size_t)N * sizeof(int);
    int* rowStart = (int*)p; p += (size_t)N * sizeof(int);
    int* cursorR  = (int*)p; p += (size_t)N * sizeof(int);
    int* jpos = (int*)p; p += (size_t)E * sizeof(int);
    int* colS = (int*)p; p += (size_t)E * sizeof(int);
    int* rs   = (int*)p; p += (size_t)E * sizeof(int);
    float* tt = (float*)p; p += (size_t)N * 3 * sizeof(float);
    float* basis = (float*)p; p += (size_t)E * 8 * sizeof(float);
    unsigned char* idxb = (unsigned char*)p; p += (size_t)E * 8;
    unsigned short* h1b = (unsigned short*)p; p += (size_t)N * 64 * sizeof(short);
    unsigned short* xb  = (unsigned short*)p; p += (size_t)N * 32 * sizeof(short);
    unsigned short* BF2 = (unsigned short*)p; p += (size_t)KC * 64 * 64 * sizeof(short);
    unsigned short* BF3 = (unsigned short*)p; p += (size_t)KC * 32 * 32 * sizeof(short);
    unsigned short* msg = (unsigned short*)p; p += (size_t)E * 64 * sizeof(short);
    size_t fixed = (size_t)(p - (char*)d_ws);
    size_t zcap = (ws_size > fixed) ? (ws_size - fixed) : 0;
    unsigned short* zbuf = (unsigned short*)p;             // conv3 z (160MB)
    // basisR/idxR alias the zbuf region (used before conv3's zgemm)
    float* basisR = (float*)zbuf;
    unsigned char* idxR = (unsigned char*)(basisR + (size_t)E * 8);

    const size_t z3_bytes = (size_t)N * KC * 32 * sizeof(short);  // 160MB
    bool fast = zcap >= z3_bytes;

    hipMemsetAsync(d_ws, 0, zero_bytes, stream);
    hist_kernel<<<(E + 255) / 256, 256, 0, stream>>>(row, col, histR, histC, E);

    if (fast) {
        pack_w_kernel<<<(KC * 64 * 64 + 255) / 256, 256, 0, stream>>>(w2, BF2, KC, 64, 64, 2, 16);
        pack_w_kernel<<<(KC * 32 * 32 + 255) / 256, 256, 0, stream>>>(wc, BF3, KC, 32, 32, 1, 32);
        castbf_kernel<<<(N * 32 + 255) / 256, 256, 0, stream>>>(x, xb, N * 32);

        scan2_kernel<<<1, 1024, 0, stream>>>(histC, histR, cstart, cursorC, rowStart, cursorR, N);
        scatterbasis_kernel<<<(E + 255) / 256, 256, 0, stream>>>(
            row, col, pseudo, cursorC, cursorR, jpos, colS, rs, basis, idxb, basisR, idxR, E);

        // conv1: streaming row-sorted basis vs LDS W1
        phaseB1s_kernel<<<(N + 3) / 4, 256, 0, stream>>>(w1, basisR, idxR, rowStart,
                                                         histR, b1, h1b, N);
        // conv2: fused MFMA-in-LDS, 4 splits, split-major msg planes
        fusedconv_kernel<2, 4><<<(N + 15) / 16, 512, 0, stream>>>(
            h1b, BF2, basis, idxb, cstart, colS, rs, msg, N, E);
        phaseBs2stn_kernel<<<(N + 3) / 4, 256, 0, stream>>>(msg, rowStart, histR, b2,
                                                            w3, b3, w4, b4, tt, N, E);
        basis2_kernel<<<(E + 255) / 256, 256, 0, stream>>>(pseudo, tt, row, col, jpos,
                                                           basis, idxb, E);
        // conv3: unfused zgemm + msgA (z3 in ws; overwrites basisR region)
        {
            dim3 g((N + 127) / 128, (250 + 3) / 4);
            zgemm_kernel<1><<<g, 256, 0, stream>>>(xb, N, BF3, zbuf, KC * 32, 0, 250);
            msgA_kernel<32, 4><<<(N + 3) / 4, 256, 0, stream>>>(
                zbuf, basis, idxb, cstart, colS, rs, msg, 32, 0, N, E);
        }
        phaseBs3_kernel<<<(N + 7) / 8, 256, 0, stream>>>(msg, rowStart, histR, cb, out, N);
    } else {
        // tiny-ws fallback: direct convs with atomics (correct, slow)
        float* acc1 = (float*)msg;
        float* acc2 = acc1 + (size_t)N * 64;
        float* acc3 = acc2 + (size_t)N * 64;
        float* h1f  = acc3 + (size_t)N * 32;
        float* h2f_ = h1f  + (size_t)N * 64;
        size_t acc_bytes = (size_t)N * (64 + 64 + 32) * sizeof(float);
        hipMemsetAsync((void*)acc1, 0, acc_bytes, stream);

        basis1_kernel<<<(E + 255) / 256, 256, 0, stream>>>(pseudo, nullptr, basis, idxb, E);
        conv1_at_kernel<<<(E + 3) / 4, 256, 0, stream>>>(basis, idxb, row, w1, acc1, E);
        finalize_kernel<<<(N * 64 + 255) / 256, 256, 0, stream>>>(acc1, histR, b1, h1f, nullptr, N, 64, 1);
        conv2f_kernel<<<(E + 3) / 4, 256, 0, stream>>>(h1f, basis, idxb, row, col, w2, acc2, E);
        finalize_kernel<<<(N * 64 + 255) / 256, 256, 0, stream>>>(acc2, histR, b2, h2f_, nullptr, N, 64, 1);
        stn34_kernel<<<N, 64, 0, stream>>>(h2f_, w3, b3, w4, b4, tt, N);
        basis2_kernel<<<(E + 255) / 256, 256, 0, stream>>>(pseudo, tt, row, col, nullptr, basis, idxb, E);
        conv3f_kernel<<<(E + 3) / 4, 256, 0, stream>>>(x, basis, idxb, row, col, wc, acc3, E);
        finalize_kernel<<<(N * 32 + 255) / 256, 256, 0, stream>>>(acc3, histR, cb, out, nullptr, N, 32, 0);
    }
}

// Round 11
// 395.030 us; speedup vs baseline: 1.5522x; 1.0646x over previous
//
#include <hip/hip_runtime.h>
#include <hip/hip_bf16.h>
#include <math.h>

// InvGraphConv: SplineCNN block on MI355X.
// N=20000, E=320000, D=3, KS=5 -> K=125, S=8, Fin=Fout=32, hidden=64.
//
// R11: BOTH convs fused (MFMA-in-LDS, 512 thr, split-major msg planes).
// conv2 = fusedconv<2,4> (proven 123us), conv3 = fusedconv<1,2> (new; replaces
// zgemm+msgA, z never in HBM). conv1 = row-sorted basis stream vs LDS W1.

typedef short  s16x8 __attribute__((ext_vector_type(8)));
typedef float  f32x4 __attribute__((ext_vector_type(4)));

__device__ __forceinline__ unsigned short f2b(float f) {
    __hip_bfloat16 h = __float2bfloat16(f);
    return __builtin_bit_cast(unsigned short, h);
}
__device__ __forceinline__ unsigned short f2h(float f) {
    _Float16 h = (_Float16)f;
    return __builtin_bit_cast(unsigned short, h);
}
__device__ __forceinline__ float h2f(unsigned short u) {
    _Float16 h = __builtin_bit_cast(_Float16, u);
    return (float)h;
}

__device__ __forceinline__ void spline8(const float u0, const float u1, const float u2,
                                        float* __restrict__ b, int* __restrict__ id) {
    const float u[3] = {u0, u1, u2};
    const int strides[3] = {25, 5, 1};
    float fr[3];
    int   i0[3];
#pragma unroll
    for (int d = 0; d < 3; ++d) {
        float p = u[d] * 4.0f;
        float f = floorf(p);
        f = fminf(fmaxf(f, 0.0f), 3.0f);
        i0[d] = (int)f;
        fr[d] = p - f;
    }
#pragma unroll
    for (int s = 0; s < 8; ++s) {
        float bb = 1.0f;
        int   ii = 0;
#pragma unroll
        for (int d = 0; d < 3; ++d) {
            int c = (s >> d) & 1;
            bb *= c ? fr[d] : (1.0f - fr[d]);
            ii += (i0[d] + c) * strides[d];
        }
        b[s] = bb;
        id[s] = ii;
    }
}

__global__ void hist_kernel(const int* __restrict__ row, const int* __restrict__ col,
                            int* __restrict__ histR, int* __restrict__ histC, int E) {
    int e = blockIdx.x * blockDim.x + threadIdx.x;
    if (e >= E) return;
    atomicAdd(&histR[row[e]], 1);
    atomicAdd(&histC[col[e]], 1);
}

// dual single-block exclusive scan
__global__ __launch_bounds__(1024) void scan2_kernel(
        const int* __restrict__ histC, const int* __restrict__ histR,
        int* __restrict__ cstart, int* __restrict__ cursorC,
        int* __restrict__ rowStart, int* __restrict__ cursorR, int N) {
    __shared__ int wsX[16], wsY[16];
    __shared__ int carX, carY;
    int t = threadIdx.x, lane = t & 63, w = t >> 6;
    if (t == 0) { carX = 0; carY = 0; }
    __syncthreads();
    for (int base = 0; base < N; base += 1024) {
        int i = base + t;
        int vx = (i < N) ? histC[i] : 0;
        int vy = (i < N) ? histR[i] : 0;
        int sx = vx, sy = vy;
#pragma unroll
        for (int off = 1; off < 64; off <<= 1) {
            int ux = __shfl_up(sx, off);
            int uy = __shfl_up(sy, off);
            if (lane >= off) { sx += ux; sy += uy; }
        }
        if (lane == 63) { wsX[w] = sx; wsY[w] = sy; }
        __syncthreads();
        if (w == 0 && lane < 16) {
            int ax = wsX[lane], ay = wsY[lane];
#pragma unroll
            for (int off = 1; off < 16; off <<= 1) {
                int ux = __shfl_up(ax, off);
                int uy = __shfl_up(ay, off);
                if (lane >= off) { ax += ux; ay += uy; }
            }
            wsX[lane] = ax; wsY[lane] = ay;
        }
        __syncthreads();
        int wx = (w > 0 ? wsX[w - 1] : 0) + carX;
        int wy = (w > 0 ? wsY[w - 1] : 0) + carY;
        if (i < N) {
            int ex = wx + sx - vx;
            int ey = wy + sy - vy;
            cstart[i] = ex; cursorC[i] = ex;
            rowStart[i] = ey; cursorR[i] = ey;
        }
        __syncthreads();
        if (t == 0) { carX += wsX[15]; carY += wsY[15]; }
        __syncthreads();
    }
}

// fused scatter + spline basis: col-sorted basis/idx AND row-sorted basisR/idxR.
__global__ void scatterbasis_kernel(
        const int* __restrict__ row, const int* __restrict__ col,
        const float* __restrict__ pseudo,
        int* __restrict__ cursorC, int* __restrict__ cursorR,
        int* __restrict__ jpos, int* __restrict__ colS, int* __restrict__ rs,
        float* __restrict__ basis, unsigned char* __restrict__ idxb,
        float* __restrict__ basisR, unsigned char* __restrict__ idxR, int E) {
    int e = blockIdx.x * blockDim.x + threadIdx.x;
    if (e >= E) return;
    int c = col[e], r = row[e];
    int jc = atomicAdd(&cursorC[c], 1);
    int jr = atomicAdd(&cursorR[r], 1);
    jpos[e] = jc;
    colS[jc] = c;
    rs[jc] = jr;
    float b[8]; int id[8];
    spline8(pseudo[e * 3 + 0], pseudo[e * 3 + 1], pseudo[e * 3 + 2], b, id);
#pragma unroll
    for (int s = 0; s < 8; ++s) {
        basis[(size_t)jc * 8 + s] = b[s];
        idxb[(size_t)jc * 8 + s] = (unsigned char)id[s];
        basisR[(size_t)jr * 8 + s] = b[s];
        idxR[(size_t)jr * 8 + s] = (unsigned char)id[s];
    }
}

__global__ void basis1_kernel(const float* __restrict__ pseudo, const int* __restrict__ jpos,
                              float* __restrict__ basis, unsigned char* __restrict__ idxb, int E) {
    int e = blockIdx.x * blockDim.x + threadIdx.x;
    if (e >= E) return;
    float b[8]; int id[8];
    spline8(pseudo[e * 3 + 0], pseudo[e * 3 + 1], pseudo[e * 3 + 2], b, id);
    int j = jpos ? jpos[e] : e;
#pragma unroll
    for (int s = 0; s < 8; ++s) { basis[(size_t)j * 8 + s] = b[s]; idxb[(size_t)j * 8 + s] = (unsigned char)id[s]; }
}

__global__ void basis2_kernel(const float* __restrict__ pseudo, const float* __restrict__ t,
                              const int* __restrict__ row, const int* __restrict__ col,
                              const int* __restrict__ jpos,
                              float* __restrict__ basis, unsigned char* __restrict__ idxb, int E) {
    int e = blockIdx.x * blockDim.x + threadIdx.x;
    if (e >= E) return;
    int r = row[e], c = col[e];
    float u[3];
#pragma unroll
    for (int d = 0; d < 3; ++d) {
        float v = pseudo[e * 3 + d] + t[c * 3 + d] - t[r * 3 + d];
        u[d] = fminf(fmaxf(v, 0.0f), 1.0f);
    }
    float b[8]; int id[8];
    spline8(u[0], u[1], u[2], b, id);
    int j = jpos ? jpos[e] : e;
#pragma unroll
    for (int s = 0; s < 8; ++s) { basis[(size_t)j * 8 + s] = b[s]; idxb[(size_t)j * 8 + s] = (unsigned char)id[s]; }
}

__global__ void castbf_kernel(const float* __restrict__ in, unsigned short* __restrict__ out,
                              int n) {
    int t = blockIdx.x * blockDim.x + threadIdx.x;
    if (t < n) out[t] = f2b(in[t]);
}

// Pack W [Kc][Fin][Fout] fp32 -> MFMA B-fragments bf16, channel-split order.
__global__ void pack_w_kernel(const float* __restrict__ W, unsigned short* __restrict__ BF,
                              int Kc, int Fin, int Fout, int ksteps, int CH) {
    int t = blockIdx.x * blockDim.x + threadIdx.x;
    int total = Kc * Fout * Fin;
    if (t >= total) return;
    int c = t / Fin;
    int i = t % Fin;
    int kk = c / Fout, o = c % Fout;
    int split = o / CH;
    int cp = split * (Kc * CH) + kk * CH + (o % CH);
    int ct = cp >> 4, lr = cp & 15;
    int step = i >> 5, rem = i & 31, lg = rem >> 3, jj = rem & 7;
    size_t dst = ((((size_t)ct * ksteps + step) * 4 + lg) * 16 + lr) * 8 + jj;
    BF[dst] = f2b(W[((size_t)kk * Fin + i) * Fout + o]);
}

// conv1 phase B: W1 in LDS; wave per row-node; streams row-sorted basisR/idxR.
__global__ __launch_bounds__(256) void phaseB1s_kernel(
        const float* __restrict__ W1, const float* __restrict__ basisR,
        const unsigned char* __restrict__ idxR, const int* __restrict__ rowStart,
        const int* __restrict__ histR, const float* __restrict__ b1,
        unsigned short* __restrict__ h1b, int N) {
    __shared__ float w[125 * 64];
    for (int i = threadIdx.x; i < 125 * 64; i += 256) w[i] = W1[i];
    __syncthreads();
    int n = blockIdx.x * 4 + (threadIdx.x >> 6);
    if (n >= N) return;
    int l = threadIdx.x & 63;
    int s0 = rowStart[n], cnt = histR[n];
    float a = 0.0f;
    for (int i = 0; i < cnt; ++i) {
        const float4* bp = (const float4*)(basisR + (size_t)(s0 + i) * 8);
        float4 b0 = bp[0], b1v = bp[1];
        const uchar4* ip = (const uchar4*)(idxR + (size_t)(s0 + i) * 8);
        uchar4 i0 = ip[0], i1 = ip[1];
        a += b0.x * w[i0.x * 64 + l] + b0.y * w[i0.y * 64 + l]
           + b0.z * w[i0.z * 64 + l] + b0.w * w[i0.w * 64 + l]
           + b1v.x * w[i1.x * 64 + l] + b1v.y * w[i1.y * 64 + l]
           + b1v.z * w[i1.z * 64 + l] + b1v.w * w[i1.w * 64 + l];
    }
    float v = a / fmaxf((float)cnt, 1.0f) + b1[l];
    v = (v > 0.0f) ? v : (expf(v) - 1.0f);
    h1b[(size_t)n * 64 + l] = f2b(v);
}

// fused conv: 512 threads, block owns 16 col-nodes. Per split s (CH=16):
// MFMA fills ztile[16][2000] fp16, edge pass stores msgs to split-major plane
// msgP[s][E][16] at row-sorted slot rs[j].
template<int KSTEPS, int SPLITS>
__global__ __launch_bounds__(512) void fusedconv_kernel(
        const unsigned short* __restrict__ A,
        const unsigned short* __restrict__ BF,
        const float* __restrict__ basis, const unsigned char* __restrict__ idxb,
        const int* __restrict__ cstart, const int* __restrict__ colS,
        const int* __restrict__ rs,
        unsigned short* __restrict__ msgP, int N, int E) {
    const int ZLD = 2008;
    __shared__ unsigned short ztile[16 * 2008];   // 64,256 B
    int n0 = blockIdx.x * 16;
    if (n0 >= N) return;
    int w = threadIdx.x >> 6, l = threadIdx.x & 63;
    int lr = l & 15, lg = l >> 4;
    const int KD = KSTEPS * 32;
    int arow = n0 + lr; if (arow > N - 1) arow = N - 1;
    s16x8 a[KSTEPS];
#pragma unroll
    for (int st = 0; st < KSTEPS; ++st)
        a[st] = *(const s16x8*)(A + (size_t)arow * KD + st * 32 + lg * 8);
    int estart = cstart[n0];
    int eend = (n0 + 16 < N) ? cstart[n0 + 16] : E;
    int g = threadIdx.x >> 4, ch = threadIdx.x & 15;   // 32 groups x 16 ch
    for (int s = 0; s < SPLITS; ++s) {
        for (int ct = w; ct < 125; ct += 8) {
            f32x4 acc = (f32x4){0.f, 0.f, 0.f, 0.f};
#pragma unroll
            for (int st = 0; st < KSTEPS; ++st) {
                const unsigned short* bp =
                    BF + ((((size_t)(s * 125 + ct) * KSTEPS + st) * 4 + lg) * 16 + lr) * 8;
                s16x8 b = *(const s16x8*)bp;
                acc = __builtin_amdgcn_mfma_f32_16x16x32_bf16(a[st], b, acc, 0, 0, 0);
            }
#pragma unroll
            for (int r = 0; r < 4; ++r)
                ztile[(lg * 4 + r) * ZLD + ct * 16 + lr] = f2h(acc[r]);
        }
        __syncthreads();
        unsigned short* mp = msgP + (size_t)s * E * 16;
        for (int j = estart + g; j < eend; j += 32) {
            int node = colS[j] - n0;
            const float4* bp = (const float4*)(basis + (size_t)j * 8);
            float4 b0 = bp[0], b1v = bp[1];
            const uchar4* ip = (const uchar4*)(idxb + (size_t)j * 8);
            uchar4 i0 = ip[0], i1 = ip[1];
            const unsigned short* zr = ztile + node * ZLD;
            float m = b0.x * h2f(zr[i0.x * 16 + ch]) + b0.y * h2f(zr[i0.y * 16 + ch])
                    + b0.z * h2f(zr[i0.z * 16 + ch]) + b0.w * h2f(zr[i0.w * 16 + ch])
                    + b1v.x * h2f(zr[i1.x * 16 + ch]) + b1v.y * h2f(zr[i1.y * 16 + ch])
                    + b1v.z * h2f(zr[i1.z * 16 + ch]) + b1v.w * h2f(zr[i1.w * 16 + ch]);
            mp[(size_t)rs[j] * 16 + ch] = f2h(m);
        }
        __syncthreads();
    }
}

// phase B conv2 + fused stn3/stn4 -> tt. Reads 4 split-major msg planes.
__global__ __launch_bounds__(256) void phaseBs2stn_kernel(
        const unsigned short* __restrict__ msgP, const int* __restrict__ rowStart,
        const int* __restrict__ histR, const float* __restrict__ b2,
        const float* __restrict__ w3, const float* __restrict__ b3,
        const float* __restrict__ w4, const float* __restrict__ b4,
        float* __restrict__ tt, int N, int E) {
    __shared__ float sh[4][64];
    __shared__ float sh3[4][64];
    int wid = threadIdx.x >> 6, l = threadIdx.x & 63;
    int n = blockIdx.x * 4 + wid;
    if (n >= N) return;
    int s0 = rowStart[n], cnt = histR[n];
    const unsigned short* mp = msgP + (size_t)(l >> 4) * E * 16 + (l & 15);
    float a = 0.0f;
    for (int i = 0; i < cnt; ++i)
        a += h2f(mp[(size_t)(s0 + i) * 16]);
    float v = a / fmaxf((float)cnt, 1.0f) + b2[l];
    v = (v > 0.0f) ? v : (expf(v) - 1.0f);
    sh[wid][l] = v;
    __builtin_amdgcn_wave_barrier();
    float v3 = b3[l];
#pragma unroll
    for (int i = 0; i < 64; ++i) v3 += sh[wid][i] * w3[i * 64 + l];
    v3 = (v3 > 0.0f) ? v3 : (expf(v3) - 1.0f);
    sh3[wid][l] = v3;
    __builtin_amdgcn_wave_barrier();
    if (l < 3) {
        float tv = b4[l];
#pragma unroll
        for (int i = 0; i < 64; ++i) tv += sh3[wid][i] * w4[i * 3 + l];
        tt[(size_t)n * 3 + l] = tv;
    }
}

// phase B conv3: half-wave per node; reads 2 split-major planes; mean+bias.
__global__ __launch_bounds__(256) void phaseBs3p_kernel(
        const unsigned short* __restrict__ msgP, const int* __restrict__ rowStart,
        const int* __restrict__ histR, const float* __restrict__ bias,
        float* __restrict__ out, int N, int E) {
    int n = blockIdx.x * 8 + (threadIdx.x >> 5);
    if (n >= N) return;
    int l = threadIdx.x & 31;
    int s0 = rowStart[n], cnt = histR[n];
    const unsigned short* mp = msgP + (size_t)(l >> 4) * E * 16 + (l & 15);
    float a = 0.0f;
    for (int i = 0; i < cnt; ++i)
        a += h2f(mp[(size_t)(s0 + i) * 16]);
    out[(size_t)n * 32 + l] = a / fmaxf((float)cnt, 1.0f) + bias[l];
}

// stn3 + stn4 per node (fallback path only)
__global__ __launch_bounds__(64) void stn34_kernel(
        const float* __restrict__ h2, const float* __restrict__ w3,
        const float* __restrict__ b3, const float* __restrict__ w4,
        const float* __restrict__ b4, float* __restrict__ t, int N) {
    int n = blockIdx.x;
    int o = threadIdx.x;
    __shared__ float sh[64];
    __shared__ float sh3[64];
    sh[o] = h2[n * 64 + o];
    __syncthreads();
    float v = b3[o];
#pragma unroll
    for (int i = 0; i < 64; ++i) v += sh[i] * w3[i * 64 + o];
    v = (v > 0.0f) ? v : (expf(v) - 1.0f);
    sh3[o] = v;
    __syncthreads();
    if (o < 3) {
        float tv = b4[o];
#pragma unroll
        for (int i = 0; i < 64; ++i) tv += sh3[i] * w4[i * 3 + o];
        t[n * 3 + o] = tv;
    }
}

// ---- minimal fallback (only if ws is tiny; direct, correct) ----
__global__ __launch_bounds__(256) void conv1_at_kernel(
        const float* __restrict__ basis, const unsigned char* __restrict__ idxb,
        const int* __restrict__ row, const float* __restrict__ W1,
        float* __restrict__ acc, int E) {
    int j = blockIdx.x * 4 + (threadIdx.x >> 6);
    if (j >= E) return;
    int l = threadIdx.x & 63;
    float m = 0.0f;
#pragma unroll
    for (int s = 0; s < 8; ++s) m += basis[(size_t)j * 8 + s] * W1[idxb[(size_t)j * 8 + s] * 64 + l];
    atomicAdd(&acc[(size_t)row[j] * 64 + l], m);
}

__global__ __launch_bounds__(256) void conv2f_kernel(
        const float* __restrict__ h1, const float* __restrict__ basis,
        const unsigned char* __restrict__ idxb, const int* __restrict__ row,
        const int* __restrict__ col, const float* __restrict__ W2,
        float* __restrict__ acc, int E) {
    int wid = threadIdx.x >> 6;
    int lane = threadIdx.x & 63;
    int e = blockIdx.x * 4 + wid;
    __shared__ float sh[4][64];
    bool active = (e < E);
    int c = active ? col[e] : 0;
    if (active) sh[wid][lane] = h1[(size_t)c * 64 + lane];
    __syncthreads();
    if (!active) return;
    float m = 0.0f;
#pragma unroll
    for (int s = 0; s < 8; ++s) {
        const float* Wk = W2 + (size_t)idxb[(size_t)e * 8 + s] * 4096;
        float ms = 0.0f;
#pragma unroll
        for (int i = 0; i < 64; ++i) ms += sh[wid][i] * Wk[i * 64 + lane];
        m += basis[(size_t)e * 8 + s] * ms;
    }
    atomicAdd(&acc[(size_t)row[e] * 64 + lane], m);
}

__global__ __launch_bounds__(256) void conv3f_kernel(
        const float* __restrict__ x, const float* __restrict__ basis,
        const unsigned char* __restrict__ idxb, const int* __restrict__ row,
        const int* __restrict__ col, const float* __restrict__ Wc,
        float* __restrict__ acc, int E) {
    int wid = threadIdx.x >> 6;
    int lane = threadIdx.x & 63;
    int e = blockIdx.x * 4 + wid;
    __shared__ float sx[4][32];
    bool active = (e < E);
    int c = active ? col[e] : 0;
    if (active && lane < 32) sx[wid][lane] = x[(size_t)c * 32 + lane];
    __syncthreads();
    int half = lane >> 5;
    int o = lane & 31;
    float m = 0.0f;
    if (active) {
#pragma unroll
        for (int s2 = 0; s2 < 4; ++s2) {
            int s = half * 4 + s2;
            const float* Wk = Wc + (size_t)idxb[(size_t)e * 8 + s] * 1024;
            float ms = 0.0f;
#pragma unroll
            for (int i = 0; i < 32; ++i) ms += sx[wid][i] * Wk[i * 32 + o];
            m += basis[(size_t)e * 8 + s] * ms;
        }
    }
    m += __shfl_xor(m, 32);
    if (active && lane < 32) atomicAdd(&acc[(size_t)row[e] * 32 + o], m);
}

__global__ void finalize_kernel(const float* __restrict__ acc, const int* __restrict__ histR,
                                const float* __restrict__ bias, float* __restrict__ outF,
                                unsigned short* __restrict__ outB,
                                int N, int F, int do_elu) {
    int t = blockIdx.x * blockDim.x + threadIdx.x;
    if (t >= N * F) return;
    int n = t / F, o = t % F;
    float v = acc[t] / fmaxf((float)histR[n], 1.0f) + bias[o];
    if (do_elu) v = (v > 0.0f) ? v : (expf(v) - 1.0f);
    if (outF) outF[t] = v;
    if (outB) outB[t] = f2b(v);
}

extern "C" void kernel_launch(void* const* d_in, const int* in_sizes, int n_in,
                              void* d_out, int out_size, void* d_ws, size_t ws_size,
                              hipStream_t stream) {
    const float* x      = (const float*)d_in[0];
    const int*   ei     = (const int*)d_in[1];
    const float* pseudo = (const float*)d_in[2];
    const float* w1     = (const float*)d_in[3];
    const float* b1     = (const float*)d_in[4];
    const float* w2     = (const float*)d_in[5];
    const float* b2     = (const float*)d_in[6];
    const float* w3     = (const float*)d_in[7];
    const float* b3     = (const float*)d_in[8];
    const float* w4     = (const float*)d_in[9];
    const float* b4     = (const float*)d_in[10];
    const float* wc     = (const float*)d_in[11];
    const float* cb     = (const float*)d_in[12];
    float* out = (float*)d_out;

    const int N = in_sizes[0] / 32;
    const int E = in_sizes[1] / 2;
    const int* row = ei;
    const int* col = ei + E;
    const int KC = 125;

    char* p = (char*)d_ws;
    // zeroed: histograms
    int* histR = (int*)p; p += (size_t)N * sizeof(int);
    int* histC = (int*)p; p += (size_t)N * sizeof(int);
    size_t zero_bytes = (size_t)(p - (char*)d_ws);
    // non-zeroed
    int* cstart   = (int*)p; p += (size_t)N * sizeof(int);
    int* cursorC  = (int*)p; p += (size_t)N * sizeof(int);
    int* rowStart = (int*)p; p += (size_t)N * sizeof(int);
    int* cursorR  = (int*)p; p += (size_t)N * sizeof(int);
    int* jpos = (int*)p; p += (size_t)E * sizeof(int);
    int* colS = (int*)p; p += (size_t)E * sizeof(int);
    int* rs   = (int*)p; p += (size_t)E * sizeof(int);
    float* tt = (float*)p; p += (size_t)N * 3 * sizeof(float);
    float* basis = (float*)p; p += (size_t)E * 8 * sizeof(float);
    unsigned char* idxb = (unsigned char*)p; p += (size_t)E * 8;
    unsigned short* h1b = (unsigned short*)p; p += (size_t)N * 64 * sizeof(short);
    unsigned short* xb  = (unsigned short*)p; p += (size_t)N * 32 * sizeof(short);
    unsigned short* BF2 = (unsigned short*)p; p += (size_t)KC * 64 * 64 * sizeof(short);
    unsigned short* BF3 = (unsigned short*)p; p += (size_t)KC * 32 * 32 * sizeof(short);
    unsigned short* msg = (unsigned short*)p; p += (size_t)E * 64 * sizeof(short);
    float* basisR = (float*)p; p += (size_t)E * 8 * sizeof(float);
    unsigned char* idxR = (unsigned char*)p; p += (size_t)E * 8;
    size_t fixed = (size_t)(p - (char*)d_ws);
    bool fast = ws_size >= fixed;

    hipMemsetAsync(d_ws, 0, zero_bytes, stream);
    hist_kernel<<<(E + 255) / 256, 256, 0, stream>>>(row, col, histR, histC, E);

    if (fast) {
        pack_w_kernel<<<(KC * 64 * 64 + 255) / 256, 256, 0, stream>>>(w2, BF2, KC, 64, 64, 2, 16);
        pack_w_kernel<<<(KC * 32 * 32 + 255) / 256, 256, 0, stream>>>(wc, BF3, KC, 32, 32, 1, 16);
        castbf_kernel<<<(N * 32 + 255) / 256, 256, 0, stream>>>(x, xb, N * 32);

        scan2_kernel<<<1, 1024, 0, stream>>>(histC, histR, cstart, cursorC, rowStart, cursorR, N);
        scatterbasis_kernel<<<(E + 255) / 256, 256, 0, stream>>>(
            row, col, pseudo, cursorC, cursorR, jpos, colS, rs, basis, idxb, basisR, idxR, E);

        // conv1: streaming row-sorted basis vs LDS W1
        phaseB1s_kernel<<<(N + 3) / 4, 256, 0, stream>>>(w1, basisR, idxR, rowStart,
                                                         histR, b1, h1b, N);
        // conv2: fused MFMA-in-LDS, 4 splits
        fusedconv_kernel<2, 4><<<(N + 15) / 16, 512, 0, stream>>>(
            h1b, BF2, basis, idxb, cstart, colS, rs, msg, N, E);
        phaseBs2stn_kernel<<<(N + 3) / 4, 256, 0, stream>>>(msg, rowStart, histR, b2,
                                                            w3, b3, w4, b4, tt, N, E);
        basis2_kernel<<<(E + 255) / 256, 256, 0, stream>>>(pseudo, tt, row, col, jpos,
                                                           basis, idxb, E);
        // conv3: fused MFMA-in-LDS, 2 splits
        fusedconv_kernel<1, 2><<<(N + 15) / 16, 512, 0, stream>>>(
            xb, BF3, basis, idxb, cstart, colS, rs, msg, N, E);
        phaseBs3p_kernel<<<(N + 7) / 8, 256, 0, stream>>>(msg, rowStart, histR, cb, out, N, E);
    } else {
        // tiny-ws fallback: direct convs with atomics (correct, slow)
        float* acc1 = (float*)msg;
        float* acc2 = acc1 + (size_t)N * 64;
        float* acc3 = acc2 + (size_t)N * 64;
        float* h1f  = acc3 + (size_t)N * 32;
        float* h2f_ = h1f  + (size_t)N * 64;
        size_t acc_bytes = (size_t)N * (64 + 64 + 32) * sizeof(float);
        hipMemsetAsync((void*)acc1, 0, acc_bytes, stream);

        basis1_kernel<<<(E + 255) / 256, 256, 0, stream>>>(pseudo, nullptr, basis, idxb, E);
        conv1_at_kernel<<<(E + 3) / 4, 256, 0, stream>>>(basis, idxb, row, w1, acc1, E);
        finalize_kernel<<<(N * 64 + 255) / 256, 256, 0, stream>>>(acc1, histR, b1, h1f, nullptr, N, 64, 1);
        conv2f_kernel<<<(E + 3) / 4, 256, 0, stream>>>(h1f, basis, idxb, row, col, w2, acc2, E);
        finalize_kernel<<<(N * 64 + 255) / 256, 256, 0, stream>>>(acc2, histR, b2, h2f_, nullptr, N, 64, 1);
        stn34_kernel<<<N, 64, 0, stream>>>(h2f_, w3, b3, w4, b4, tt, N);
        basis2_kernel<<<(E + 255) / 256, 256, 0, stream>>>(pseudo, tt, row, col, nullptr, basis, idxb, E);
        conv3f_kernel<<<(E + 3) / 4, 256, 0, stream>>>(x, basis, idxb, row, col, wc, acc3, E);
        finalize_kernel<<<(N * 32 + 255) / 256, 256, 0, stream>>>(acc3, histR, cb, out, nullptr, N, 32, 0);
    }
}

// Round 12
// 375.500 us; speedup vs baseline: 1.6329x; 1.0520x over previous
//
#include <hip/hip_runtime.h>
#include <hip/hip_bf16.h>
#include <math.h>

// InvGraphConv: SplineCNN block on MI355X.
// N=20000, E=320000, D=3, KS=5 -> K=125, S=8, Fin=Fout=32, hidden=64.
//
// R12: fusedconv latency attack: NODES=12 (ztile 48KB -> 3 blocks/CU) and
// edge pass at 2 ch/lane via packed u32 LDS reads (64 groups in flight,
// half the serial iters). Structure otherwise = R11.

typedef short  s16x8 __attribute__((ext_vector_type(8)));
typedef float  f32x4 __attribute__((ext_vector_type(4)));

__device__ __forceinline__ unsigned short f2b(float f) {
    __hip_bfloat16 h = __float2bfloat16(f);
    return __builtin_bit_cast(unsigned short, h);
}
__device__ __forceinline__ unsigned short f2h(float f) {
    _Float16 h = (_Float16)f;
    return __builtin_bit_cast(unsigned short, h);
}
__device__ __forceinline__ float h2f(unsigned short u) {
    _Float16 h = __builtin_bit_cast(_Float16, u);
    return (float)h;
}

__device__ __forceinline__ void spline8(const float u0, const float u1, const float u2,
                                        float* __restrict__ b, int* __restrict__ id) {
    const float u[3] = {u0, u1, u2};
    const int strides[3] = {25, 5, 1};
    float fr[3];
    int   i0[3];
#pragma unroll
    for (int d = 0; d < 3; ++d) {
        float p = u[d] * 4.0f;
        float f = floorf(p);
        f = fminf(fmaxf(f, 0.0f), 3.0f);
        i0[d] = (int)f;
        fr[d] = p - f;
    }
#pragma unroll
    for (int s = 0; s < 8; ++s) {
        float bb = 1.0f;
        int   ii = 0;
#pragma unroll
        for (int d = 0; d < 3; ++d) {
            int c = (s >> d) & 1;
            bb *= c ? fr[d] : (1.0f - fr[d]);
            ii += (i0[d] + c) * strides[d];
        }
        b[s] = bb;
        id[s] = ii;
    }
}

__global__ void hist_kernel(const int* __restrict__ row, const int* __restrict__ col,
                            int* __restrict__ histR, int* __restrict__ histC, int E) {
    int e = blockIdx.x * blockDim.x + threadIdx.x;
    if (e >= E) return;
    atomicAdd(&histR[row[e]], 1);
    atomicAdd(&histC[col[e]], 1);
}

// dual single-block exclusive scan
__global__ __launch_bounds__(1024) void scan2_kernel(
        const int* __restrict__ histC, const int* __restrict__ histR,
        int* __restrict__ cstart, int* __restrict__ cursorC,
        int* __restrict__ rowStart, int* __restrict__ cursorR, int N) {
    __shared__ int wsX[16], wsY[16];
    __shared__ int carX, carY;
    int t = threadIdx.x, lane = t & 63, w = t >> 6;
    if (t == 0) { carX = 0; carY = 0; }
    __syncthreads();
    for (int base = 0; base < N; base += 1024) {
        int i = base + t;
        int vx = (i < N) ? histC[i] : 0;
        int vy = (i < N) ? histR[i] : 0;
        int sx = vx, sy = vy;
#pragma unroll
        for (int off = 1; off < 64; off <<= 1) {
            int ux = __shfl_up(sx, off);
            int uy = __shfl_up(sy, off);
            if (lane >= off) { sx += ux; sy += uy; }
        }
        if (lane == 63) { wsX[w] = sx; wsY[w] = sy; }
        __syncthreads();
        if (w == 0 && lane < 16) {
            int ax = wsX[lane], ay = wsY[lane];
#pragma unroll
            for (int off = 1; off < 16; off <<= 1) {
                int ux = __shfl_up(ax, off);
                int uy = __shfl_up(ay, off);
                if (lane >= off) { ax += ux; ay += uy; }
            }
            wsX[lane] = ax; wsY[lane] = ay;
        }
        __syncthreads();
        int wx = (w > 0 ? wsX[w - 1] : 0) + carX;
        int wy = (w > 0 ? wsY[w - 1] : 0) + carY;
        if (i < N) {
            int ex = wx + sx - vx;
            int ey = wy + sy - vy;
            cstart[i] = ex; cursorC[i] = ex;
            rowStart[i] = ey; cursorR[i] = ey;
        }
        __syncthreads();
        if (t == 0) { carX += wsX[15]; carY += wsY[15]; }
        __syncthreads();
    }
}

// fused scatter + spline basis: col-sorted basis/idx AND row-sorted basisR/idxR.
__global__ void scatterbasis_kernel(
        const int* __restrict__ row, const int* __restrict__ col,
        const float* __restrict__ pseudo,
        int* __restrict__ cursorC, int* __restrict__ cursorR,
        int* __restrict__ jpos, int* __restrict__ colS, int* __restrict__ rs,
        float* __restrict__ basis, unsigned char* __restrict__ idxb,
        float* __restrict__ basisR, unsigned char* __restrict__ idxR, int E) {
    int e = blockIdx.x * blockDim.x + threadIdx.x;
    if (e >= E) return;
    int c = col[e], r = row[e];
    int jc = atomicAdd(&cursorC[c], 1);
    int jr = atomicAdd(&cursorR[r], 1);
    jpos[e] = jc;
    colS[jc] = c;
    rs[jc] = jr;
    float b[8]; int id[8];
    spline8(pseudo[e * 3 + 0], pseudo[e * 3 + 1], pseudo[e * 3 + 2], b, id);
#pragma unroll
    for (int s = 0; s < 8; ++s) {
        basis[(size_t)jc * 8 + s] = b[s];
        idxb[(size_t)jc * 8 + s] = (unsigned char)id[s];
        basisR[(size_t)jr * 8 + s] = b[s];
        idxR[(size_t)jr * 8 + s] = (unsigned char)id[s];
    }
}

__global__ void basis1_kernel(const float* __restrict__ pseudo, const int* __restrict__ jpos,
                              float* __restrict__ basis, unsigned char* __restrict__ idxb, int E) {
    int e = blockIdx.x * blockDim.x + threadIdx.x;
    if (e >= E) return;
    float b[8]; int id[8];
    spline8(pseudo[e * 3 + 0], pseudo[e * 3 + 1], pseudo[e * 3 + 2], b, id);
    int j = jpos ? jpos[e] : e;
#pragma unroll
    for (int s = 0; s < 8; ++s) { basis[(size_t)j * 8 + s] = b[s]; idxb[(size_t)j * 8 + s] = (unsigned char)id[s]; }
}

__global__ void basis2_kernel(const float* __restrict__ pseudo, const float* __restrict__ t,
                              const int* __restrict__ row, const int* __restrict__ col,
                              const int* __restrict__ jpos,
                              float* __restrict__ basis, unsigned char* __restrict__ idxb, int E) {
    int e = blockIdx.x * blockDim.x + threadIdx.x;
    if (e >= E) return;
    int r = row[e], c = col[e];
    float u[3];
#pragma unroll
    for (int d = 0; d < 3; ++d) {
        float v = pseudo[e * 3 + d] + t[c * 3 + d] - t[r * 3 + d];
        u[d] = fminf(fmaxf(v, 0.0f), 1.0f);
    }
    float b[8]; int id[8];
    spline8(u[0], u[1], u[2], b, id);
    int j = jpos ? jpos[e] : e;
#pragma unroll
    for (int s = 0; s < 8; ++s) { basis[(size_t)j * 8 + s] = b[s]; idxb[(size_t)j * 8 + s] = (unsigned char)id[s]; }
}

__global__ void castbf_kernel(const float* __restrict__ in, unsigned short* __restrict__ out,
                              int n) {
    int t = blockIdx.x * blockDim.x + threadIdx.x;
    if (t < n) out[t] = f2b(in[t]);
}

// Pack W [Kc][Fin][Fout] fp32 -> MFMA B-fragments bf16, channel-split order.
__global__ void pack_w_kernel(const float* __restrict__ W, unsigned short* __restrict__ BF,
                              int Kc, int Fin, int Fout, int ksteps, int CH) {
    int t = blockIdx.x * blockDim.x + threadIdx.x;
    int total = Kc * Fout * Fin;
    if (t >= total) return;
    int c = t / Fin;
    int i = t % Fin;
    int kk = c / Fout, o = c % Fout;
    int split = o / CH;
    int cp = split * (Kc * CH) + kk * CH + (o % CH);
    int ct = cp >> 4, lr = cp & 15;
    int step = i >> 5, rem = i & 31, lg = rem >> 3, jj = rem & 7;
    size_t dst = ((((size_t)ct * ksteps + step) * 4 + lg) * 16 + lr) * 8 + jj;
    BF[dst] = f2b(W[((size_t)kk * Fin + i) * Fout + o]);
}

// conv1 phase B: W1 in LDS; wave per row-node; streams row-sorted basisR/idxR.
__global__ __launch_bounds__(256) void phaseB1s_kernel(
        const float* __restrict__ W1, const float* __restrict__ basisR,
        const unsigned char* __restrict__ idxR, const int* __restrict__ rowStart,
        const int* __restrict__ histR, const float* __restrict__ b1,
        unsigned short* __restrict__ h1b, int N) {
    __shared__ float w[125 * 64];
    for (int i = threadIdx.x; i < 125 * 64; i += 256) w[i] = W1[i];
    __syncthreads();
    int n = blockIdx.x * 4 + (threadIdx.x >> 6);
    if (n >= N) return;
    int l = threadIdx.x & 63;
    int s0 = rowStart[n], cnt = histR[n];
    float a = 0.0f;
    for (int i = 0; i < cnt; ++i) {
        const float4* bp = (const float4*)(basisR + (size_t)(s0 + i) * 8);
        float4 b0 = bp[0], b1v = bp[1];
        const uchar4* ip = (const uchar4*)(idxR + (size_t)(s0 + i) * 8);
        uchar4 i0 = ip[0], i1 = ip[1];
        a += b0.x * w[i0.x * 64 + l] + b0.y * w[i0.y * 64 + l]
           + b0.z * w[i0.z * 64 + l] + b0.w * w[i0.w * 64 + l]
           + b1v.x * w[i1.x * 64 + l] + b1v.y * w[i1.y * 64 + l]
           + b1v.z * w[i1.z * 64 + l] + b1v.w * w[i1.w * 64 + l];
    }
    float v = a / fmaxf((float)cnt, 1.0f) + b1[l];
    v = (v > 0.0f) ? v : (expf(v) - 1.0f);
    h1b[(size_t)n * 64 + l] = f2b(v);
}

// fused conv: 512 threads, block owns NODES col-nodes. Per split s (CH=16):
// MFMA fills ztile[NODES][2000] fp16; edge pass (64 groups x 8 ch-pairs,
// packed u32 reads) stores msgs to split-major plane msgP[s][E][16] at rs[j].
template<int KSTEPS, int SPLITS, int NODES>
__global__ __launch_bounds__(512) void fusedconv_kernel(
        const unsigned short* __restrict__ A,
        const unsigned short* __restrict__ BF,
        const float* __restrict__ basis, const unsigned char* __restrict__ idxb,
        const int* __restrict__ cstart, const int* __restrict__ colS,
        const int* __restrict__ rs,
        unsigned short* __restrict__ msgP, int N, int E) {
    const int ZLD = 2008;
    __shared__ unsigned short ztile[NODES * 2008];
    int n0 = blockIdx.x * NODES;
    if (n0 >= N) return;
    int w = threadIdx.x >> 6, l = threadIdx.x & 63;
    int lr = l & 15, lg = l >> 4;
    const int KD = KSTEPS * 32;
    int arow = n0 + lr; if (arow > N - 1) arow = N - 1;
    s16x8 a[KSTEPS];
#pragma unroll
    for (int st = 0; st < KSTEPS; ++st)
        a[st] = *(const s16x8*)(A + (size_t)arow * KD + st * 32 + lg * 8);
    int estart = cstart[n0];
    int eend = (n0 + NODES < N) ? cstart[n0 + NODES] : E;
    int g = threadIdx.x >> 3, chp = threadIdx.x & 7;   // 64 groups x 8 ch-pairs
    for (int s = 0; s < SPLITS; ++s) {
        for (int ct = w; ct < 125; ct += 8) {
            f32x4 acc = (f32x4){0.f, 0.f, 0.f, 0.f};
#pragma unroll
            for (int st = 0; st < KSTEPS; ++st) {
                const unsigned short* bp =
                    BF + ((((size_t)(s * 125 + ct) * KSTEPS + st) * 4 + lg) * 16 + lr) * 8;
                s16x8 b = *(const s16x8*)bp;
                acc = __builtin_amdgcn_mfma_f32_16x16x32_bf16(a[st], b, acc, 0, 0, 0);
            }
#pragma unroll
            for (int r = 0; r < 4; ++r) {
                int rl = lg * 4 + r;
                if (rl < NODES)
                    ztile[rl * ZLD + ct * 16 + lr] = f2h(acc[r]);
            }
        }
        __syncthreads();
        unsigned int* mp = (unsigned int*)(msgP + (size_t)s * E * 16);
        for (int j = estart + g; j < eend; j += 64) {
            int node = colS[j] - n0;
            const float4* bp = (const float4*)(basis + (size_t)j * 8);
            float4 b0 = bp[0], b1v = bp[1];
            const uchar4* ip = (const uchar4*)(idxb + (size_t)j * 8);
            uchar4 i0 = ip[0], i1 = ip[1];
            const unsigned int* zr = (const unsigned int*)(ztile + node * ZLD);
            unsigned int v0 = zr[i0.x * 8 + chp];
            unsigned int v1 = zr[i0.y * 8 + chp];
            unsigned int v2 = zr[i0.z * 8 + chp];
            unsigned int v3 = zr[i0.w * 8 + chp];
            unsigned int v4 = zr[i1.x * 8 + chp];
            unsigned int v5 = zr[i1.y * 8 + chp];
            unsigned int v6 = zr[i1.z * 8 + chp];
            unsigned int v7 = zr[i1.w * 8 + chp];
            float mlo = b0.x * h2f(v0 & 0xffff) + b0.y * h2f(v1 & 0xffff)
                      + b0.z * h2f(v2 & 0xffff) + b0.w * h2f(v3 & 0xffff)
                      + b1v.x * h2f(v4 & 0xffff) + b1v.y * h2f(v5 & 0xffff)
                      + b1v.z * h2f(v6 & 0xffff) + b1v.w * h2f(v7 & 0xffff);
            float mhi = b0.x * h2f(v0 >> 16) + b0.y * h2f(v1 >> 16)
                      + b0.z * h2f(v2 >> 16) + b0.w * h2f(v3 >> 16)
                      + b1v.x * h2f(v4 >> 16) + b1v.y * h2f(v5 >> 16)
                      + b1v.z * h2f(v6 >> 16) + b1v.w * h2f(v7 >> 16);
            unsigned int packed = (unsigned int)f2h(mlo) | ((unsigned int)f2h(mhi) << 16);
            mp[(size_t)rs[j] * 8 + chp] = packed;
        }
        __syncthreads();
    }
}

// phase B conv2 + fused stn3/stn4 -> tt. Reads 4 split-major msg planes.
__global__ __launch_bounds__(256) void phaseBs2stn_kernel(
        const unsigned short* __restrict__ msgP, const int* __restrict__ rowStart,
        const int* __restrict__ histR, const float* __restrict__ b2,
        const float* __restrict__ w3, const float* __restrict__ b3,
        const float* __restrict__ w4, const float* __restrict__ b4,
        float* __restrict__ tt, int N, int E) {
    __shared__ float sh[4][64];
    __shared__ float sh3[4][64];
    int wid = threadIdx.x >> 6, l = threadIdx.x & 63;
    int n = blockIdx.x * 4 + wid;
    if (n >= N) return;
    int s0 = rowStart[n], cnt = histR[n];
    const unsigned short* mp = msgP + (size_t)(l >> 4) * E * 16 + (l & 15);
    float a = 0.0f;
    for (int i = 0; i < cnt; ++i)
        a += h2f(mp[(size_t)(s0 + i) * 16]);
    float v = a / fmaxf((float)cnt, 1.0f) + b2[l];
    v = (v > 0.0f) ? v : (expf(v) - 1.0f);
    sh[wid][l] = v;
    __builtin_amdgcn_wave_barrier();
    float v3 = b3[l];
#pragma unroll
    for (int i = 0; i < 64; ++i) v3 += sh[wid][i] * w3[i * 64 + l];
    v3 = (v3 > 0.0f) ? v3 : (expf(v3) - 1.0f);
    sh3[wid][l] = v3;
    __builtin_amdgcn_wave_barrier();
    if (l < 3) {
        float tv = b4[l];
#pragma unroll
        for (int i = 0; i < 64; ++i) tv += sh3[wid][i] * w4[i * 3 + l];
        tt[(size_t)n * 3 + l] = tv;
    }
}

// phase B conv3: half-wave per node; reads 2 split-major planes; mean+bias.
__global__ __launch_bounds__(256) void phaseBs3p_kernel(
        const unsigned short* __restrict__ msgP, const int* __restrict__ rowStart,
        const int* __restrict__ histR, const float* __restrict__ bias,
        float* __restrict__ out, int N, int E) {
    int n = blockIdx.x * 8 + (threadIdx.x >> 5);
    if (n >= N) return;
    int l = threadIdx.x & 31;
    int s0 = rowStart[n], cnt = histR[n];
    const unsigned short* mp = msgP + (size_t)(l >> 4) * E * 16 + (l & 15);
    float a = 0.0f;
    for (int i = 0; i < cnt; ++i)
        a += h2f(mp[(size_t)(s0 + i) * 16]);
    out[(size_t)n * 32 + l] = a / fmaxf((float)cnt, 1.0f) + bias[l];
}

// stn3 + stn4 per node (fallback path only)
__global__ __launch_bounds__(64) void stn34_kernel(
        const float* __restrict__ h2, const float* __restrict__ w3,
        const float* __restrict__ b3, const float* __restrict__ w4,
        const float* __restrict__ b4, float* __restrict__ t, int N) {
    int n = blockIdx.x;
    int o = threadIdx.x;
    __shared__ float sh[64];
    __shared__ float sh3[64];
    sh[o] = h2[n * 64 + o];
    __syncthreads();
    float v = b3[o];
#pragma unroll
    for (int i = 0; i < 64; ++i) v += sh[i] * w3[i * 64 + o];
    v = (v > 0.0f) ? v : (expf(v) - 1.0f);
    sh3[o] = v;
    __syncthreads();
    if (o < 3) {
        float tv = b4[o];
#pragma unroll
        for (int i = 0; i < 64; ++i) tv += sh3[i] * w4[i * 3 + o];
        t[n * 3 + o] = tv;
    }
}

// ---- minimal fallback (only if ws is tiny; direct, correct) ----
__global__ __launch_bounds__(256) void conv1_at_kernel(
        const float* __restrict__ basis, const unsigned char* __restrict__ idxb,
        const int* __restrict__ row, const float* __restrict__ W1,
        float* __restrict__ acc, int E) {
    int j = blockIdx.x * 4 + (threadIdx.x >> 6);
    if (j >= E) return;
    int l = threadIdx.x & 63;
    float m = 0.0f;
#pragma unroll
    for (int s = 0; s < 8; ++s) m += basis[(size_t)j * 8 + s] * W1[idxb[(size_t)j * 8 + s] * 64 + l];
    atomicAdd(&acc[(size_t)row[j] * 64 + l], m);
}

__global__ __launch_bounds__(256) void conv2f_kernel(
        const float* __restrict__ h1, const float* __restrict__ basis,
        const unsigned char* __restrict__ idxb, const int* __restrict__ row,
        const int* __restrict__ col, const float* __restrict__ W2,
        float* __restrict__ acc, int E) {
    int wid = threadIdx.x >> 6;
    int lane = threadIdx.x & 63;
    int e = blockIdx.x * 4 + wid;
    __shared__ float sh[4][64];
    bool active = (e < E);
    int c = active ? col[e] : 0;
    if (active) sh[wid][lane] = h1[(size_t)c * 64 + lane];
    __syncthreads();
    if (!active) return;
    float m = 0.0f;
#pragma unroll
    for (int s = 0; s < 8; ++s) {
        const float* Wk = W2 + (size_t)idxb[(size_t)e * 8 + s] * 4096;
        float ms = 0.0f;
#pragma unroll
        for (int i = 0; i < 64; ++i) ms += sh[wid][i] * Wk[i * 64 + lane];
        m += basis[(size_t)e * 8 + s] * ms;
    }
    atomicAdd(&acc[(size_t)row[e] * 64 + lane], m);
}

__global__ __launch_bounds__(256) void conv3f_kernel(
        const float* __restrict__ x, const float* __restrict__ basis,
        const unsigned char* __restrict__ idxb, const int* __restrict__ row,
        const int* __restrict__ col, const float* __restrict__ Wc,
        float* __restrict__ acc, int E) {
    int wid = threadIdx.x >> 6;
    int lane = threadIdx.x & 63;
    int e = blockIdx.x * 4 + wid;
    __shared__ float sx[4][32];
    bool active = (e < E);
    int c = active ? col[e] : 0;
    if (active && lane < 32) sx[wid][lane] = x[(size_t)c * 32 + lane];
    __syncthreads();
    int half = lane >> 5;
    int o = lane & 31;
    float m = 0.0f;
    if (active) {
#pragma unroll
        for (int s2 = 0; s2 < 4; ++s2) {
            int s = half * 4 + s2;
            const float* Wk = Wc + (size_t)idxb[(size_t)e * 8 + s] * 1024;
            float ms = 0.0f;
#pragma unroll
            for (int i = 0; i < 32; ++i) ms += sx[wid][i] * Wk[i * 32 + o];
            m += basis[(size_t)e * 8 + s] * ms;
        }
    }
    m += __shfl_xor(m, 32);
    if (active && lane < 32) atomicAdd(&acc[(size_t)row[e] * 32 + o], m);
}

__global__ void finalize_kernel(const float* __restrict__ acc, const int* __restrict__ histR,
                                const float* __restrict__ bias, float* __restrict__ outF,
                                unsigned short* __restrict__ outB,
                                int N, int F, int do_elu) {
    int t = blockIdx.x * blockDim.x + threadIdx.x;
    if (t >= N * F) return;
    int n = t / F, o = t % F;
    float v = acc[t] / fmaxf((float)histR[n], 1.0f) + bias[o];
    if (do_elu) v = (v > 0.0f) ? v : (expf(v) - 1.0f);
    if (outF) outF[t] = v;
    if (outB) outB[t] = f2b(v);
}

extern "C" void kernel_launch(void* const* d_in, const int* in_sizes, int n_in,
                              void* d_out, int out_size, void* d_ws, size_t ws_size,
                              hipStream_t stream) {
    const float* x      = (const float*)d_in[0];
    const int*   ei     = (const int*)d_in[1];
    const float* pseudo = (const float*)d_in[2];
    const float* w1     = (const float*)d_in[3];
    const float* b1     = (const float*)d_in[4];
    const float* w2     = (const float*)d_in[5];
    const float* b2     = (const float*)d_in[6];
    const float* w3     = (const float*)d_in[7];
    const float* b3     = (const float*)d_in[8];
    const float* w4     = (const float*)d_in[9];
    const float* b4     = (const float*)d_in[10];
    const float* wc     = (const float*)d_in[11];
    const float* cb     = (const float*)d_in[12];
    float* out = (float*)d_out;

    const int N = in_sizes[0] / 32;
    const int E = in_sizes[1] / 2;
    const int* row = ei;
    const int* col = ei + E;
    const int KC = 125;
    const int NODES = 12;

    char* p = (char*)d_ws;
    // zeroed: histograms
    int* histR = (int*)p; p += (size_t)N * sizeof(int);
    int* histC = (int*)p; p += (size_t)N * sizeof(int);
    size_t zero_bytes = (size_t)(p - (char*)d_ws);
    // non-zeroed
    int* cstart   = (int*)p; p += (size_t)N * sizeof(int);
    int* cursorC  = (int*)p; p += (size_t)N * sizeof(int);
    int* rowStart = (int*)p; p += (size_t)N * sizeof(int);
    int* cursorR  = (int*)p; p += (size_t)N * sizeof(int);
    int* jpos = (int*)p; p += (size_t)E * sizeof(int);
    int* colS = (int*)p; p += (size_t)E * sizeof(int);
    int* rs   = (int*)p; p += (size_t)E * sizeof(int);
    float* tt = (float*)p; p += (size_t)N * 3 * sizeof(float);
    float* basis = (float*)p; p += (size_t)E * 8 * sizeof(float);
    unsigned char* idxb = (unsigned char*)p; p += (size_t)E * 8;
    unsigned short* h1b = (unsigned short*)p; p += (size_t)N * 64 * sizeof(short);
    unsigned short* xb  = (unsigned short*)p; p += (size_t)N * 32 * sizeof(short);
    unsigned short* BF2 = (unsigned short*)p; p += (size_t)KC * 64 * 64 * sizeof(short);
    unsigned short* BF3 = (unsigned short*)p; p += (size_t)KC * 32 * 32 * sizeof(short);
    unsigned short* msg = (unsigned short*)p; p += (size_t)E * 64 * sizeof(short);
    float* basisR = (float*)p; p += (size_t)E * 8 * sizeof(float);
    unsigned char* idxR = (unsigned char*)p; p += (size_t)E * 8;
    size_t fixed = (size_t)(p - (char*)d_ws);
    bool fast = ws_size >= fixed;

    hipMemsetAsync(d_ws, 0, zero_bytes, stream);
    hist_kernel<<<(E + 255) / 256, 256, 0, stream>>>(row, col, histR, histC, E);

    if (fast) {
        pack_w_kernel<<<(KC * 64 * 64 + 255) / 256, 256, 0, stream>>>(w2, BF2, KC, 64, 64, 2, 16);
        pack_w_kernel<<<(KC * 32 * 32 + 255) / 256, 256, 0, stream>>>(wc, BF3, KC, 32, 32, 1, 16);
        castbf_kernel<<<(N * 32 + 255) / 256, 256, 0, stream>>>(x, xb, N * 32);

        scan2_kernel<<<1, 1024, 0, stream>>>(histC, histR, cstart, cursorC, rowStart, cursorR, N);
        scatterbasis_kernel<<<(E + 255) / 256, 256, 0, stream>>>(
            row, col, pseudo, cursorC, cursorR, jpos, colS, rs, basis, idxb, basisR, idxR, E);

        // conv1: streaming row-sorted basis vs LDS W1
        phaseB1s_kernel<<<(N + 3) / 4, 256, 0, stream>>>(w1, basisR, idxR, rowStart,
                                                         histR, b1, h1b, N);
        const int NB = (N + NODES - 1) / NODES;
        // conv2: fused MFMA-in-LDS, 4 splits
        fusedconv_kernel<2, 4, 12><<<NB, 512, 0, stream>>>(
            h1b, BF2, basis, idxb, cstart, colS, rs, msg, N, E);
        phaseBs2stn_kernel<<<(N + 3) / 4, 256, 0, stream>>>(msg, rowStart, histR, b2,
                                                            w3, b3, w4, b4, tt, N, E);
        basis2_kernel<<<(E + 255) / 256, 256, 0, stream>>>(pseudo, tt, row, col, jpos,
                                                           basis, idxb, E);
        // conv3: fused MFMA-in-LDS, 2 splits
        fusedconv_kernel<1, 2, 12><<<NB, 512, 0, stream>>>(
            xb, BF3, basis, idxb, cstart, colS, rs, msg, N, E);
        phaseBs3p_kernel<<<(N + 7) / 8, 256, 0, stream>>>(msg, rowStart, histR, cb, out, N, E);
    } else {
        // tiny-ws fallback: direct convs with atomics (correct, slow)
        float* acc1 = (float*)msg;
        float* acc2 = acc1 + (size_t)N * 64;
        float* acc3 = acc2 + (size_t)N * 64;
        float* h1f  = acc3 + (size_t)N * 32;
        float* h2f_ = h1f  + (size_t)N * 64;
        size_t acc_bytes = (size_t)N * (64 + 64 + 32) * sizeof(float);
        hipMemsetAsync((void*)acc1, 0, acc_bytes, stream);

        basis1_kernel<<<(E + 255) / 256, 256, 0, stream>>>(pseudo, nullptr, basis, idxb, E);
        conv1_at_kernel<<<(E + 3) / 4, 256, 0, stream>>>(basis, idxb, row, w1, acc1, E);
        finalize_kernel<<<(N * 64 + 255) / 256, 256, 0, stream>>>(acc1, histR, b1, h1f, nullptr, N, 64, 1);
        conv2f_kernel<<<(E + 3) / 4, 256, 0, stream>>>(h1f, basis, idxb, row, col, w2, acc2, E);
        finalize_kernel<<<(N * 64 + 255) / 256, 256, 0, stream>>>(acc2, histR, b2, h2f_, nullptr, N, 64, 1);
        stn34_kernel<<<N, 64, 0, stream>>>(h2f_, w3, b3, w4, b4, tt, N);
        basis2_kernel<<<(E + 255) / 256, 256, 0, stream>>>(pseudo, tt, row, col, nullptr, basis, idxb, E);
        conv3f_kernel<<<(E + 3) / 4, 256, 0, stream>>>(x, basis, idxb, row, col, wc, acc3, E);
        finalize_kernel<<<(N * 32 + 255) / 256, 256, 0, stream>>>(acc3, histR, cb, out, nullptr, N, 32, 0);
    }
}